// Round 3
// baseline (368.680 us; speedup 1.0000x reference)
//
#include <hip/hip_runtime.h>

// Problem constants (fixed by the reference)
#define NN     100000      // nodes
#define EE     1600000     // edges
#define NB     8           // graphs
#define BLK    12500       // nodes per graph
#define HID    128
#define KC     4
#define CHUNKS 196         // ceil(12500/64)
#define SCANB  196         // scan blocks (512 nodes each)

typedef __attribute__((ext_vector_type(8))) short bf16x8;
typedef __attribute__((ext_vector_type(4))) float f32x4;

__device__ __forceinline__ ushort f2bf(float f) {
  uint u = __float_as_uint(f);
  return (ushort)((u + 0x7FFFu + ((u >> 16) & 1u)) >> 16);  // RNE
}
__device__ __forceinline__ float bf2f(ushort h) {
  return __uint_as_float(((uint)h) << 16);
}

// ---------------------------------------------------------------- K0a: x -> bf16
__global__ __launch_bounds__(256) void k_prep_x(const float4* __restrict__ x4,
                                                ushort* __restrict__ xb) {
  int i = blockIdx.x * 256 + threadIdx.x;  // 3.2M float4s exactly
  float4 v = x4[i];
  ushort4 r;
  r.x = f2bf(v.x); r.y = f2bf(v.y); r.z = f2bf(v.z); r.w = f2bf(v.w);
  *(ushort4*)(xb + (size_t)i * 4) = r;
}

// ---------------------------------------------------------------- K0b: Wt[col][k], k<128 = Wrel1, k>=128 = Wroot1
__global__ __launch_bounds__(256) void k_prep_w(const float* __restrict__ Wrel1,
                                                const float* __restrict__ Wroot1,
                                                ushort* __restrict__ Wt) {
  int col = blockIdx.x, k = threadIdx.x;
  float v = (k < 128) ? Wrel1[k * 128 + col] : Wroot1[(k - 128) * 128 + col];
  Wt[col * 256 + k] = f2bf(v);
}

// ---------------------------------------------------------------- K1a: degree histogram
__global__ __launch_bounds__(256) void k_count(const int* __restrict__ ei,
                                               int* __restrict__ count) {
  int e = blockIdx.x * 256 + threadIdx.x;
  if (e >= EE) return;
  atomicAdd(&count[ei[EE + e]], 1);
}

// ---------------------------------------------------------------- K1b: scan phase A — per-block (512 nodes) sums
__global__ __launch_bounds__(256) void k_scanA(const int* __restrict__ count,
                                               int* __restrict__ blocksum) {
  __shared__ int sd[256];
  const int t = threadIdx.x;
  int i0 = blockIdx.x * 512 + 2 * t;
  int v = 0;
  if (i0 < NN) v += count[i0];
  if (i0 + 1 < NN) v += count[i0 + 1];
  sd[t] = v;
  __syncthreads();
  for (int off = 128; off > 0; off >>= 1) {
    if (t < off) sd[t] += sd[t + off];
    __syncthreads();
  }
  if (t == 0) blocksum[blockIdx.x] = sd[0];
}

// ---------------------------------------------------------------- K1c: scan phase B — exclusive scan of block sums
__global__ __launch_bounds__(256) void k_scanB(int* __restrict__ blocksum) {
  __shared__ int sd[256];
  const int t = threadIdx.x;
  int v = (t < SCANB) ? blocksum[t] : 0;
  sd[t] = v;
  __syncthreads();
  for (int off = 1; off < 256; off <<= 1) {
    int x = (t >= off) ? sd[t - off] : 0;
    __syncthreads();
    sd[t] += x;
    __syncthreads();
  }
  if (t < SCANB) blocksum[t] = sd[t] - v;  // exclusive
}

// ---------------------------------------------------------------- K1d: scan phase C — rowptr + cursor
__global__ __launch_bounds__(256) void k_scanC(const int* __restrict__ count,
                                               const int* __restrict__ blocksum,
                                               int* __restrict__ rowptr,
                                               int* __restrict__ cursor) {
  __shared__ int sd[256];
  const int t = threadIdx.x;
  const int base = blocksum[blockIdx.x];
  int i0 = blockIdx.x * 512 + 2 * t;
  int c0 = (i0 < NN) ? count[i0] : 0;
  int c1 = (i0 + 1 < NN) ? count[i0 + 1] : 0;
  int v = c0 + c1;
  sd[t] = v;
  __syncthreads();
  for (int off = 1; off < 256; off <<= 1) {
    int x = (t >= off) ? sd[t - off] : 0;
    __syncthreads();
    sd[t] += x;
    __syncthreads();
  }
  int excl = base + sd[t] - v;
  if (i0 < NN) { rowptr[i0] = excl; cursor[i0] = excl; }
  if (i0 + 1 < NN) { rowptr[i0 + 1] = excl + c0; cursor[i0 + 1] = excl + c0; }
}

// ---------------------------------------------------------------- K1e: fill CSR (cursor starts at rowptr -> absolute pos)
__global__ __launch_bounds__(256) void k_fill(const int* __restrict__ ei,
                                              int* __restrict__ cursor,
                                              int* __restrict__ csr) {
  int e = blockIdx.x * 256 + threadIdx.x;
  if (e >= EE) return;
  int src = ei[e];
  int dst = ei[EE + e];
  int pos = atomicAdd(&cursor[dst], 1);
  csr[pos] = src;
}

// ---------------------------------------------------------------- K2: agg[n] = sum_{e: dst=n} x[src]  (bf16, fp32 accum)
// XCD-aware: blockIdx%8 selects the graph so each XCD's L2 holds one graph's
// 3.2 MB x-slice.
__global__ __launch_bounds__(256) void k_agg2(const ushort* __restrict__ xb,
                                              const int* __restrict__ count,
                                              const int* __restrict__ rowptr,
                                              const int* __restrict__ csr,
                                              ushort* __restrict__ aggb) {
  const int xg = blockIdx.x & 7;
  const int j = blockIdx.x >> 3;
  const int half = threadIdx.x >> 5;  // 8 half-waves = 8 nodes per block
  const int lane = threadIdx.x & 31;
  const int ln = j * 8 + half;
  if (ln >= BLK) return;
  const int node = xg * BLK + ln;
  const int deg = count[node];
  const int* sl = csr + rowptr[node];
  int idx0 = (lane < deg) ? sl[lane] : 0;
  int idx1 = (32 + lane < deg) ? sl[32 + lane] : 0;
  float a0 = 0.f, a1 = 0.f, a2 = 0.f, a3 = 0.f;
  for (int e = 0; e < deg; ++e) {
    int srcn = (e < 32) ? __shfl(idx0, e, 32)
                        : ((e < 64) ? __shfl(idx1, e - 32, 32) : sl[e]);
    ushort4 v = *(const ushort4*)(xb + (size_t)srcn * HID + lane * 4);
    a0 += bf2f(v.x); a1 += bf2f(v.y); a2 += bf2f(v.z); a3 += bf2f(v.w);
  }
  ushort4 r;
  r.x = f2bf(a0); r.y = f2bf(a1); r.z = f2bf(a2); r.w = f2bf(a3);
  *(ushort4*)(aggb + (size_t)node * HID + lane * 4) = r;
}

// ---------------------------------------------------------------- K3: MFMA GEMM + softmax + pooled reductions
__global__ __launch_bounds__(256) void k_fused(
    const ushort* __restrict__ aggb, const ushort* __restrict__ xb,
    const ushort* __restrict__ Wt, const float* __restrict__ brel1,
    const float* __restrict__ Wpool, const float* __restrict__ bpool,
    const int* __restrict__ count, float* __restrict__ s_out,
    float* __restrict__ out_pool, float* __restrict__ ss_g,
    float* __restrict__ den_g) {
  __shared__ ushort As[64][40];    // 64 rows x 32 k (pad->40)
  __shared__ ushort Bs[128][40];   // 128 cols x 32 k
  __shared__ float hL[64][132];    // h tile (pad 128->132)
  __shared__ float outL[KC][HID];
  __shared__ float ssL[16];
  __shared__ float denL;

  const int t = threadIdx.x;
  const int bG = blockIdx.x / CHUNKS;
  const int chunk = blockIdx.x % CHUNKS;
  const int node0 = bG * BLK + chunk * 64;
  int nrows = BLK - chunk * 64;
  if (nrows > 64) nrows = 64;

  for (int i = t; i < KC * HID; i += 256) ((float*)outL)[i] = 0.f;
  if (t < 16) ssL[t] = 0.f;
  if (t == 0) denL = 0.f;

  const int w = t >> 6;     // wave: cols 32w..32w+31
  const int l = t & 63;
  const int m16 = l & 15;
  const int gq = l >> 4;

  f32x4 acc[4][2];
#pragma unroll
  for (int fr = 0; fr < 4; ++fr)
#pragma unroll
    for (int fc = 0; fc < 2; ++fc) acc[fr][fc] = (f32x4){0.f, 0.f, 0.f, 0.f};

  const int arow = t >> 2;
  const int acol = (t & 3) * 8;
  const int arr = (arow < nrows) ? arow : (nrows - 1);
  const ushort* Aag = aggb + (size_t)(node0 + arr) * HID + acol;
  const ushort* Axx = xb + (size_t)(node0 + arr) * HID + acol;

#pragma unroll 1
  for (int kt = 0; kt < 8; ++kt) {
    const int kb = (kt & 3) * 32;
    __syncthreads();
    {
      const ushort* srcp = (kt < 4) ? (Aag + kb) : (Axx + kb);
      *(uint4*)&As[arow][acol] = *(const uint4*)srcp;
#pragma unroll
      for (int i = 0; i < 2; ++i) {
        int idx = i * 256 + t;
        int col = idx >> 2, ch = (idx & 3) * 8;
        *(uint4*)&Bs[col][ch] = *(const uint4*)(Wt + (size_t)col * 256 + kt * 32 + ch);
      }
    }
    __syncthreads();
    bf16x8 af[4], bfr[2];
#pragma unroll
    for (int fr = 0; fr < 4; ++fr)
      af[fr] = *(const bf16x8*)&As[16 * fr + m16][8 * gq];
#pragma unroll
    for (int fc = 0; fc < 2; ++fc)
      bfr[fc] = *(const bf16x8*)&Bs[32 * w + 16 * fc + m16][8 * gq];
#pragma unroll
    for (int fr = 0; fr < 4; ++fr)
#pragma unroll
      for (int fc = 0; fc < 2; ++fc)
        acc[fr][fc] = __builtin_amdgcn_mfma_f32_16x16x32_bf16(af[fr], bfr[fc],
                                                              acc[fr][fc], 0, 0, 0);
  }

  // bias + relu -> hL  (D layout: row = 4*(l>>4)+reg, col = l&15  [m89])
  const float bc0 = brel1[32 * w + m16];
  const float bc1 = brel1[32 * w + 16 + m16];
#pragma unroll
  for (int fr = 0; fr < 4; ++fr)
#pragma unroll
    for (int fc = 0; fc < 2; ++fc)
#pragma unroll
      for (int r = 0; r < 4; ++r)
        hL[16 * fr + 4 * gq + r][32 * w + 16 * fc + m16] =
            fmaxf(acc[fr][fc][r] + (fc ? bc1 : bc0), 0.f);
  __syncthreads();

  // ---- epilogue (16-lane groups own 4 rows each) ----
  const int g4 = t >> 4;
  const int c0 = (t & 15) << 2;
  const int li = t & 15;

  float h[4][8];
#pragma unroll
  for (int r = 0; r < 4; ++r) {
    float4 v0 = *(const float4*)&hL[g4 * 4 + r][c0];
    float4 v1 = *(const float4*)&hL[g4 * 4 + r][c0 + 64];
    h[r][0] = v0.x; h[r][1] = v0.y; h[r][2] = v0.z; h[r][3] = v0.w;
    h[r][4] = v1.x; h[r][5] = v1.y; h[r][6] = v1.z; h[r][7] = v1.w;
  }

  // pooling head: p = h @ Wpool
  float wp[8][4];
#pragma unroll
  for (int j = 0; j < 8; ++j) {
    int col = c0 + (j & 3) + (j >> 2) * 64;
    float4 v = *(const float4*)(Wpool + col * 4);
    wp[j][0] = v.x; wp[j][1] = v.y; wp[j][2] = v.z; wp[j][3] = v.w;
  }
  float pp[4][4];
#pragma unroll
  for (int r = 0; r < 4; ++r)
#pragma unroll
    for (int k = 0; k < 4; ++k) pp[r][k] = 0.f;
#pragma unroll
  for (int r = 0; r < 4; ++r)
#pragma unroll
    for (int j = 0; j < 8; ++j)
#pragma unroll
      for (int k = 0; k < 4; ++k) pp[r][k] = fmaf(h[r][j], wp[j][k], pp[r][k]);
#pragma unroll
  for (int m = 1; m <= 8; m <<= 1)
#pragma unroll
    for (int r = 0; r < 4; ++r)
#pragma unroll
      for (int k = 0; k < 4; ++k) pp[r][k] += __shfl_xor(pp[r][k], m);

  float4 bp4 = *(const float4*)bpool;
  float bp[4] = {bp4.x, bp4.y, bp4.z, bp4.w};
  float sv[4][4];
#pragma unroll
  for (int r = 0; r < 4; ++r) {
    float p[4];
#pragma unroll
    for (int k = 0; k < 4; ++k) p[k] = pp[r][k] + bp[k];
    float mx = fmaxf(fmaxf(p[0], p[1]), fmaxf(p[2], p[3]));
    float e0 = expf(p[0] - mx), e1 = expf(p[1] - mx), e2 = expf(p[2] - mx), e3 = expf(p[3] - mx);
    float inv = 1.f / (e0 + e1 + e2 + e3);
    float valid = (g4 * 4 + r < nrows) ? 1.f : 0.f;
    sv[r][0] = e0 * inv * valid; sv[r][1] = e1 * inv * valid;
    sv[r][2] = e2 * inv * valid; sv[r][3] = e3 * inv * valid;
  }

  // write s
  {
    int rW = li >> 2, kW = li & 3;
    if (g4 * 4 + rW < nrows) {
      int node = node0 + g4 * 4 + rW;
      float val = 0.f;
#pragma unroll
      for (int rr = 0; rr < 4; ++rr)
#pragma unroll
        for (int kk = 0; kk < 4; ++kk)
          if (li == rr * 4 + kk) val = sv[rr][kk];
      s_out[node * 4 + kW] = val;
    }
  }

  // ss[b][k1][k2]
  {
    int k1 = li >> 2, k2 = li & 3;
    float a1[4], a2[4];
#pragma unroll
    for (int rr = 0; rr < 4; ++rr) {
      float v1 = 0.f, v2 = 0.f;
#pragma unroll
      for (int kk = 0; kk < 4; ++kk) {
        if (k1 == kk) v1 = sv[rr][kk];
        if (k2 == kk) v2 = sv[rr][kk];
      }
      a1[rr] = v1; a2[rr] = v2;
    }
    float ssv = a1[0] * a2[0] + a1[1] * a2[1] + a1[2] * a2[2] + a1[3] * a2[3];
    atomicAdd(&ssL[li], ssv);
  }

  // den[b] += deg * ||s||^2
  if (li == 0) {
    float dent = 0.f;
#pragma unroll
    for (int rr = 0; rr < 4; ++rr) {
      int rowg = g4 * 4 + rr;
      if (rowg < nrows) {
        float dg = (float)count[node0 + rowg];
        dent += dg * (sv[rr][0] * sv[rr][0] + sv[rr][1] * sv[rr][1] +
                      sv[rr][2] * sv[rr][2] + sv[rr][3] * sv[rr][3]);
      }
    }
    atomicAdd(&denL, dent);
  }

  // out[b][k][c] += s[r][k]*h[r][c]
  float po[4][8];
#pragma unroll
  for (int k = 0; k < 4; ++k)
#pragma unroll
    for (int c = 0; c < 8; ++c) po[k][c] = 0.f;
#pragma unroll
  for (int k = 0; k < 4; ++k)
#pragma unroll
    for (int rr = 0; rr < 4; ++rr)
#pragma unroll
      for (int c = 0; c < 8; ++c) po[k][c] = fmaf(sv[rr][k], h[rr][c], po[k][c]);
#pragma unroll
  for (int k = 0; k < 4; ++k)
#pragma unroll
    for (int c = 0; c < 8; ++c) {
      po[k][c] += __shfl_xor(po[k][c], 16);
      po[k][c] += __shfl_xor(po[k][c], 32);
    }
  if ((t & 63) < 16) {
#pragma unroll
    for (int k = 0; k < 4; ++k)
#pragma unroll
      for (int c = 0; c < 8; ++c)
        atomicAdd(&outL[k][c0 + (c & 3) + (c >> 2) * 64], po[k][c]);
  }

  __syncthreads();
  for (int i = t; i < KC * HID; i += 256)
    atomicAdd(&out_pool[bG * KC * HID + i], ((const float*)outL)[i]);
  if (t < 16) atomicAdd(&ss_g[bG * 16 + t], ssL[t]);
  if (t == 0) atomicAdd(&den_g[bG], denL);
}

// ---------------------------------------------------------------- K4: out_adj[b] = sum_n s[n] (x) t[n],  t[n] = sum_{e: dst=n} s[src]
__global__ __launch_bounds__(256) void k_adj2(const int* __restrict__ count,
                                              const int* __restrict__ rowptr,
                                              const int* __restrict__ csr,
                                              const float* __restrict__ s,
                                              float* __restrict__ adjraw) {
  __shared__ float accL[4][2][16];  // [wave][graph-within-block][k1*4+k2]
  const int t = threadIdx.x;
  if (t < 128) ((float*)accL)[t] = 0.f;
  __syncthreads();
  const int node = blockIdx.x * 256 + t;
  const int g0 = (blockIdx.x * 256) / BLK;
  if (node < NN) {
    const int gi = node / BLK - g0;  // 0 or 1
    const int deg = count[node];
    const int* sl = csr + rowptr[node];
    float t0 = 0.f, t1 = 0.f, t2 = 0.f, t3 = 0.f;
    for (int e = 0; e < deg; ++e) {
      float4 svv = *(const float4*)(s + (size_t)sl[e] * 4);
      t0 += svv.x; t1 += svv.y; t2 += svv.z; t3 += svv.w;
    }
    float4 sn = *(const float4*)(s + (size_t)node * 4);
    float* base = accL[t >> 6][gi];
#pragma unroll
    for (int i = 0; i < 16; ++i) {
      int idx = (i + t) & 15;  // stagger: 4-way instead of 64-way contention
      int hi = idx >> 2, lo = idx & 3;
      float a = (hi == 0) ? sn.x : (hi == 1) ? sn.y : (hi == 2) ? sn.z : sn.w;
      float b = (lo == 0) ? t0 : (lo == 1) ? t1 : (lo == 2) ? t2 : t3;
      atomicAdd(base + idx, a * b);
    }
  }
  __syncthreads();
  if (t < 32) {
    int gi = t >> 4, i = t & 15, gg = g0 + gi;
    if (gg < NB) {
      float v = accL[0][gi][i] + accL[1][gi][i] + accL[2][gi][i] + accL[3][gi][i];
      atomicAdd(&adjraw[gg * 16 + i], v);
    }
  }
}

// ---------------------------------------------------------------- K5a: per-graph tail
__global__ __launch_bounds__(128) void k_graph(
    const float* __restrict__ out_pool, const float* __restrict__ adjraw,
    const float* __restrict__ den_g, const float* __restrict__ ss_g,
    const float* __restrict__ Wrel3, const float* __restrict__ brel3,
    const float* __restrict__ Wroot3, const float* __restrict__ Wlin1,
    const float* __restrict__ blin1, const float* __restrict__ Wlin2,
    const float* __restrict__ blin2, float* __restrict__ d_out,
    float* __restrict__ scratch) {
  const int b = blockIdx.x, t = threadIdx.x;
  __shared__ float adjL[16], adjnL[16], dL[4];
  __shared__ float osL[128], msL[128], x2mL[128], x3L[128];
  if (t < 16) adjL[t] = adjraw[b * 16 + t];
  __syncthreads();
  if (t < 4) {
    float srow = 0.f;
#pragma unroll
    for (int l = 0; l < 4; ++l)
      if (l != t) srow += adjL[t * 4 + l];
    dL[t] = sqrtf(srow) + 1e-15f;
  }
  __syncthreads();
  if (t < 16) {
    int k1 = t >> 2, k2 = t & 3;
    float az = (k1 == k2) ? 0.f : adjL[t];
    float an = az / (dL[k2] * dL[k1]);
    adjnL[t] = an;
    d_out[400018 + b * 16 + t] = an;
  }
  __syncthreads();
  float o0 = out_pool[b * 512 + 0 * 128 + t];
  float o1 = out_pool[b * 512 + 1 * 128 + t];
  float o2 = out_pool[b * 512 + 2 * 128 + t];
  float o3 = out_pool[b * 512 + 3 * 128 + t];
  float m0 = adjnL[0] * o0 + adjnL[1] * o1 + adjnL[2] * o2 + adjnL[3] * o3;
  float m1 = adjnL[4] * o0 + adjnL[5] * o1 + adjnL[6] * o2 + adjnL[7] * o3;
  float m2 = adjnL[8] * o0 + adjnL[9] * o1 + adjnL[10] * o2 + adjnL[11] * o3;
  float m3 = adjnL[12] * o0 + adjnL[13] * o1 + adjnL[14] * o2 + adjnL[15] * o3;
  osL[t] = o0 + o1 + o2 + o3;
  msL[t] = m0 + m1 + m2 + m3;
  __syncthreads();
  float accc = brel3[t];
  for (int j = 0; j < 128; ++j)
    accc += 0.25f * (msL[j] * Wrel3[j * 128 + t] + osL[j] * Wroot3[j * 128 + t]);
  x2mL[t] = accc;
  __syncthreads();
  float a2 = blin1[t];
  for (int j = 0; j < 128; ++j) a2 += x2mL[j] * Wlin1[j * 128 + t];
  x3L[t] = fmaxf(a2, 0.f);
  __syncthreads();
  if (t < 2) {
    float lg = blin2[t];
    for (int j = 0; j < 128; ++j) lg += x3L[j] * Wlin2[j * 2 + t];
    scratch[b * 2 + t] = lg;
  }
  if (t == 0) {
    float tr = adjL[0] + adjL[5] + adjL[10] + adjL[15];
    scratch[16 + b] = tr / den_g[b];
    float n2 = 0.f;
    for (int i = 0; i < 16; ++i) { float v = ss_g[b * 16 + i]; n2 += v * v; }
    float nn = sqrtf(n2);
    float od = 0.f;
    for (int i = 0; i < 16; ++i) {
      float v = ss_g[b * 16 + i] / nn - (((i >> 2) == (i & 3)) ? 0.5f : 0.f);
      od += v * v;
    }
    scratch[24 + b] = sqrtf(od);
  }
}

// ---------------------------------------------------------------- K5b: losses + log_softmax
__global__ void k_final(const float* __restrict__ scratch, float* __restrict__ d_out) {
  if (threadIdx.x == 0 && blockIdx.x == 0) {
    float mc = 0.f, oo = 0.f;
    for (int b = 0; b < NB; ++b) { mc += scratch[16 + b]; oo += scratch[24 + b]; }
    d_out[16] = -(mc / (float)NB);
    d_out[17] = oo / (float)NB;
    for (int b = 0; b < NB; ++b) {
      float l0 = scratch[2 * b], l1 = scratch[2 * b + 1];
      float m = fmaxf(l0, l1);
      float lse = m + logf(expf(l0 - m) + expf(l1 - m));
      d_out[2 * b] = l0 - lse;
      d_out[2 * b + 1] = l1 - lse;
    }
  }
}

// ---------------------------------------------------------------- launch
extern "C" void kernel_launch(void* const* d_in, const int* in_sizes, int n_in,
                              void* d_out, int out_size, void* d_ws, size_t ws_size,
                              hipStream_t stream) {
  (void)in_sizes; (void)n_in; (void)out_size; (void)ws_size;
  const float* x      = (const float*)d_in[0];
  const int*   ei     = (const int*)d_in[1];
  const float* Wroot1 = (const float*)d_in[3];
  const float* Wrel1  = (const float*)d_in[4];
  const float* brel1  = (const float*)d_in[5];
  const float* Wpool  = (const float*)d_in[6];
  const float* bpool  = (const float*)d_in[7];
  const float* Wrel3  = (const float*)d_in[8];
  const float* brel3  = (const float*)d_in[9];
  const float* Wroot3 = (const float*)d_in[10];
  const float* Wlin1  = (const float*)d_in[11];
  const float* blin1  = (const float*)d_in[12];
  const float* Wlin2  = (const float*)d_in[13];
  const float* blin2  = (const float*)d_in[14];
  float* out = (float*)d_out;

  char* ws = (char*)d_ws;
  int*    count    = (int*)(ws + 0);            //   400000 B (memset)
  float*  out_pool = (float*)(ws + 400000);     //    16384 B (memset)
  float*  ss_g     = (float*)(ws + 416384);     //      512 B (memset)
  float*  adjraw   = (float*)(ws + 416896);     //      512 B (memset)
  float*  den_g    = (float*)(ws + 417408);     //       32 B (memset)
  float*  scratch  = (float*)(ws + 417440);     //      128 B (memset)
  int*    rowptr   = (int*)(ws + 417568);       //   400016 B
  int*    cursor   = (int*)(ws + 817584);       //   400016 B
  int*    blocksum = (int*)(ws + 1217600);      //     1024 B
  ushort* Wt       = (ushort*)(ws + 1218624);   //    65536 B [128][256]
  int*    csr      = (int*)(ws + 1284160);      //  6400000 B [E]
  ushort* xb       = (ushort*)(ws + 7684160);   // 25600000 B [N][128] bf16
  ushort* aggb     = (ushort*)(ws + 33284160);  // 25600000 B [N][128] bf16

  hipMemsetAsync(ws, 0, 417568, stream);
  k_prep_x<<<12500, 256, 0, stream>>>((const float4*)x, xb);
  k_prep_w<<<128, 256, 0, stream>>>(Wrel1, Wroot1, Wt);
  k_count<<<(EE + 255) / 256, 256, 0, stream>>>(ei, count);
  k_scanA<<<SCANB, 256, 0, stream>>>(count, blocksum);
  k_scanB<<<1, 256, 0, stream>>>(blocksum);
  k_scanC<<<SCANB, 256, 0, stream>>>(count, blocksum, rowptr, cursor);
  k_fill<<<(EE + 255) / 256, 256, 0, stream>>>(ei, cursor, csr);
  k_agg2<<<8 * ((BLK + 7) / 8), 256, 0, stream>>>(xb, count, rowptr, csr, aggb);
  k_fused<<<NB * CHUNKS, 256, 0, stream>>>(aggb, xb, Wt, brel1, Wpool, bpool, count,
                                           out + 18, out_pool, ss_g, den_g);
  k_adj2<<<(NN + 255) / 256, 256, 0, stream>>>(count, rowptr, csr, out + 18, adjraw);
  k_graph<<<NB, 128, 0, stream>>>(out_pool, adjraw, den_g, ss_g, Wrel3, brel3, Wroot3,
                                  Wlin1, blin1, Wlin2, blin2, out, scratch);
  k_final<<<1, 64, 0, stream>>>(scratch, out);
}

// Round 4
// 346.359 us; speedup vs baseline: 1.0644x; 1.0644x over previous
//
#include <hip/hip_runtime.h>

// Problem constants (fixed by the reference)
#define NN     100000      // nodes
#define EE     1600000     // edges
#define NB     8           // graphs
#define BLK    12500       // nodes per graph
#define HID    128
#define KC     4
#define CHUNKS 196         // ceil(12500/64)
#define SCANB  196         // scan blocks (512 nodes each)

typedef __attribute__((ext_vector_type(8))) short bf16x8;
typedef __attribute__((ext_vector_type(4))) float f32x4;

__device__ __forceinline__ ushort f2bf(float f) {
  uint u = __float_as_uint(f);
  return (ushort)((u + 0x7FFFu + ((u >> 16) & 1u)) >> 16);  // RNE
}
__device__ __forceinline__ float bf2f(ushort h) {
  return __uint_as_float(((uint)h) << 16);
}

// ---------------------------------------------------------------- K0a: x -> bf16
__global__ __launch_bounds__(256) void k_prep_x(const float4* __restrict__ x4,
                                                ushort* __restrict__ xb) {
  int i = blockIdx.x * 256 + threadIdx.x;  // 3.2M float4s exactly
  float4 v = x4[i];
  ushort4 r;
  r.x = f2bf(v.x); r.y = f2bf(v.y); r.z = f2bf(v.z); r.w = f2bf(v.w);
  *(ushort4*)(xb + (size_t)i * 4) = r;
}

// ---------------------------------------------------------------- K0b: Wt[col][k], k<128 = Wrel1, k>=128 = Wroot1
__global__ __launch_bounds__(256) void k_prep_w(const float* __restrict__ Wrel1,
                                                const float* __restrict__ Wroot1,
                                                ushort* __restrict__ Wt) {
  int col = blockIdx.x, k = threadIdx.x;
  float v = (k < 128) ? Wrel1[k * 128 + col] : Wroot1[(k - 128) * 128 + col];
  Wt[col * 256 + k] = f2bf(v);
}

// ---------------------------------------------------------------- K1a: degree histogram
__global__ __launch_bounds__(256) void k_count(const int* __restrict__ ei,
                                               int* __restrict__ count) {
  int e = blockIdx.x * 256 + threadIdx.x;
  if (e >= EE) return;
  atomicAdd(&count[ei[EE + e]], 1);
}

// ---------------------------------------------------------------- K1b: scan phase A — per-block (512 nodes) sums
__global__ __launch_bounds__(256) void k_scanA(const int* __restrict__ count,
                                               int* __restrict__ blocksum) {
  __shared__ int sd[256];
  const int t = threadIdx.x;
  int i0 = blockIdx.x * 512 + 2 * t;
  int v = 0;
  if (i0 < NN) v += count[i0];
  if (i0 + 1 < NN) v += count[i0 + 1];
  sd[t] = v;
  __syncthreads();
  for (int off = 128; off > 0; off >>= 1) {
    if (t < off) sd[t] += sd[t + off];
    __syncthreads();
  }
  if (t == 0) blocksum[blockIdx.x] = sd[0];
}

// ---------------------------------------------------------------- K1c: scan phase B — exclusive scan of block sums
__global__ __launch_bounds__(256) void k_scanB(int* __restrict__ blocksum) {
  __shared__ int sd[256];
  const int t = threadIdx.x;
  int v = (t < SCANB) ? blocksum[t] : 0;
  sd[t] = v;
  __syncthreads();
  for (int off = 1; off < 256; off <<= 1) {
    int x = (t >= off) ? sd[t - off] : 0;
    __syncthreads();
    sd[t] += x;
    __syncthreads();
  }
  if (t < SCANB) blocksum[t] = sd[t] - v;  // exclusive
}

// ---------------------------------------------------------------- K1d: scan phase C — rowptr + cursor
__global__ __launch_bounds__(256) void k_scanC(const int* __restrict__ count,
                                               const int* __restrict__ blocksum,
                                               int* __restrict__ rowptr,
                                               int* __restrict__ cursor) {
  __shared__ int sd[256];
  const int t = threadIdx.x;
  const int base = blocksum[blockIdx.x];
  int i0 = blockIdx.x * 512 + 2 * t;
  int c0 = (i0 < NN) ? count[i0] : 0;
  int c1 = (i0 + 1 < NN) ? count[i0 + 1] : 0;
  int v = c0 + c1;
  sd[t] = v;
  __syncthreads();
  for (int off = 1; off < 256; off <<= 1) {
    int x = (t >= off) ? sd[t - off] : 0;
    __syncthreads();
    sd[t] += x;
    __syncthreads();
  }
  int excl = base + sd[t] - v;
  if (i0 < NN) { rowptr[i0] = excl; cursor[i0] = excl; }
  if (i0 + 1 < NN) { rowptr[i0 + 1] = excl + c0; cursor[i0 + 1] = excl + c0; }
}

// ---------------------------------------------------------------- K1e: fill CSR, XCD-local by graph
// Block b handles ONLY graph b%8's edges (blockIdx%8 -> XCD round-robin), so
// the scattered csr/cursor writes for one graph (800 KB / 50 KB slices) stay
// in a single XCD's 4 MB L2 and write back line-dense (~6.4 MB total instead
// of 1.6M x 64 B). Perf heuristic only: correctness doesn't depend on the
// XCD mapping.
__global__ __launch_bounds__(256) void k_fill_g(const int* __restrict__ ei,
                                                int* __restrict__ cursor,
                                                int* __restrict__ csr) {
  const int g = blockIdx.x & 7;
  const int chunk = blockIdx.x >> 3;
  const int nchunk = gridDim.x >> 3;
  const int lo = g * BLK, hi = lo + BLK;
  const int per = (EE + nchunk - 1) / nchunk;
  const int e0 = chunk * per;
  int e1 = e0 + per;
  if (e1 > EE) e1 = EE;
  for (int e = e0 + threadIdx.x; e < e1; e += 256) {
    int dst = ei[EE + e];
    if (dst >= lo && dst < hi) {
      int src = ei[e];
      int pos = atomicAdd(&cursor[dst], 1);
      csr[pos] = src;
    }
  }
}

// ---------------------------------------------------------------- K2: agg[n] = sum_{e: dst=n} x[src]  (bf16, fp32 accum)
// XCD-aware: blockIdx%8 selects the graph so each XCD's L2 holds one graph's
// 3.2 MB x-slice.
__global__ __launch_bounds__(256) void k_agg2(const ushort* __restrict__ xb,
                                              const int* __restrict__ count,
                                              const int* __restrict__ rowptr,
                                              const int* __restrict__ csr,
                                              ushort* __restrict__ aggb) {
  const int xg = blockIdx.x & 7;
  const int j = blockIdx.x >> 3;
  const int half = threadIdx.x >> 5;  // 8 half-waves = 8 nodes per block
  const int lane = threadIdx.x & 31;
  const int ln = j * 8 + half;
  if (ln >= BLK) return;
  const int node = xg * BLK + ln;
  const int deg = count[node];
  const int* sl = csr + rowptr[node];
  int idx0 = (lane < deg) ? sl[lane] : 0;
  int idx1 = (32 + lane < deg) ? sl[32 + lane] : 0;
  float a0 = 0.f, a1 = 0.f, a2 = 0.f, a3 = 0.f;
  for (int e = 0; e < deg; ++e) {
    int srcn = (e < 32) ? __shfl(idx0, e, 32)
                        : ((e < 64) ? __shfl(idx1, e - 32, 32) : sl[e]);
    ushort4 v = *(const ushort4*)(xb + (size_t)srcn * HID + lane * 4);
    a0 += bf2f(v.x); a1 += bf2f(v.y); a2 += bf2f(v.z); a3 += bf2f(v.w);
  }
  ushort4 r;
  r.x = f2bf(a0); r.y = f2bf(a1); r.z = f2bf(a2); r.w = f2bf(a3);
  *(ushort4*)(aggb + (size_t)node * HID + lane * 4) = r;
}

// ---------------------------------------------------------------- K3: MFMA GEMM + softmax + pooled reductions
__global__ __launch_bounds__(256) void k_fused(
    const ushort* __restrict__ aggb, const ushort* __restrict__ xb,
    const ushort* __restrict__ Wt, const float* __restrict__ brel1,
    const float* __restrict__ Wpool, const float* __restrict__ bpool,
    const int* __restrict__ count, float* __restrict__ s_out,
    float* __restrict__ out_pool, float* __restrict__ ss_g,
    float* __restrict__ den_g) {
  __shared__ ushort As[64][40];    // 64 rows x 32 k (pad->40)
  __shared__ ushort Bs[128][40];   // 128 cols x 32 k
  __shared__ float hL[64][132];    // h tile (pad 128->132)
  __shared__ float outL[KC][HID];
  __shared__ float ssL[16];
  __shared__ float denL;

  const int t = threadIdx.x;
  const int bG = blockIdx.x / CHUNKS;
  const int chunk = blockIdx.x % CHUNKS;
  const int node0 = bG * BLK + chunk * 64;
  int nrows = BLK - chunk * 64;
  if (nrows > 64) nrows = 64;

  for (int i = t; i < KC * HID; i += 256) ((float*)outL)[i] = 0.f;
  if (t < 16) ssL[t] = 0.f;
  if (t == 0) denL = 0.f;

  const int w = t >> 6;     // wave: cols 32w..32w+31
  const int l = t & 63;
  const int m16 = l & 15;
  const int gq = l >> 4;

  f32x4 acc[4][2];
#pragma unroll
  for (int fr = 0; fr < 4; ++fr)
#pragma unroll
    for (int fc = 0; fc < 2; ++fc) acc[fr][fc] = (f32x4){0.f, 0.f, 0.f, 0.f};

  const int arow = t >> 2;
  const int acol = (t & 3) * 8;
  const int arr = (arow < nrows) ? arow : (nrows - 1);
  const ushort* Aag = aggb + (size_t)(node0 + arr) * HID + acol;
  const ushort* Axx = xb + (size_t)(node0 + arr) * HID + acol;

#pragma unroll 1
  for (int kt = 0; kt < 8; ++kt) {
    const int kb = (kt & 3) * 32;
    __syncthreads();
    {
      const ushort* srcp = (kt < 4) ? (Aag + kb) : (Axx + kb);
      *(uint4*)&As[arow][acol] = *(const uint4*)srcp;
#pragma unroll
      for (int i = 0; i < 2; ++i) {
        int idx = i * 256 + t;
        int col = idx >> 2, ch = (idx & 3) * 8;
        *(uint4*)&Bs[col][ch] = *(const uint4*)(Wt + (size_t)col * 256 + kt * 32 + ch);
      }
    }
    __syncthreads();
    bf16x8 af[4], bfr[2];
#pragma unroll
    for (int fr = 0; fr < 4; ++fr)
      af[fr] = *(const bf16x8*)&As[16 * fr + m16][8 * gq];
#pragma unroll
    for (int fc = 0; fc < 2; ++fc)
      bfr[fc] = *(const bf16x8*)&Bs[32 * w + 16 * fc + m16][8 * gq];
#pragma unroll
    for (int fr = 0; fr < 4; ++fr)
#pragma unroll
      for (int fc = 0; fc < 2; ++fc)
        acc[fr][fc] = __builtin_amdgcn_mfma_f32_16x16x32_bf16(af[fr], bfr[fc],
                                                              acc[fr][fc], 0, 0, 0);
  }

  // bias + relu -> hL  (D layout: row = 4*(l>>4)+reg, col = l&15  [m89])
  const float bc0 = brel1[32 * w + m16];
  const float bc1 = brel1[32 * w + 16 + m16];
#pragma unroll
  for (int fr = 0; fr < 4; ++fr)
#pragma unroll
    for (int fc = 0; fc < 2; ++fc)
#pragma unroll
      for (int r = 0; r < 4; ++r)
        hL[16 * fr + 4 * gq + r][32 * w + 16 * fc + m16] =
            fmaxf(acc[fr][fc][r] + (fc ? bc1 : bc0), 0.f);
  __syncthreads();

  // ---- epilogue (16-lane groups own 4 rows each) ----
  const int g4 = t >> 4;
  const int c0 = (t & 15) << 2;
  const int li = t & 15;

  float h[4][8];
#pragma unroll
  for (int r = 0; r < 4; ++r) {
    float4 v0 = *(const float4*)&hL[g4 * 4 + r][c0];
    float4 v1 = *(const float4*)&hL[g4 * 4 + r][c0 + 64];
    h[r][0] = v0.x; h[r][1] = v0.y; h[r][2] = v0.z; h[r][3] = v0.w;
    h[r][4] = v1.x; h[r][5] = v1.y; h[r][6] = v1.z; h[r][7] = v1.w;
  }

  // pooling head: p = h @ Wpool
  float wp[8][4];
#pragma unroll
  for (int j = 0; j < 8; ++j) {
    int col = c0 + (j & 3) + (j >> 2) * 64;
    float4 v = *(const float4*)(Wpool + col * 4);
    wp[j][0] = v.x; wp[j][1] = v.y; wp[j][2] = v.z; wp[j][3] = v.w;
  }
  float pp[4][4];
#pragma unroll
  for (int r = 0; r < 4; ++r)
#pragma unroll
    for (int k = 0; k < 4; ++k) pp[r][k] = 0.f;
#pragma unroll
  for (int r = 0; r < 4; ++r)
#pragma unroll
    for (int j = 0; j < 8; ++j)
#pragma unroll
      for (int k = 0; k < 4; ++k) pp[r][k] = fmaf(h[r][j], wp[j][k], pp[r][k]);
#pragma unroll
  for (int m = 1; m <= 8; m <<= 1)
#pragma unroll
    for (int r = 0; r < 4; ++r)
#pragma unroll
      for (int k = 0; k < 4; ++k) pp[r][k] += __shfl_xor(pp[r][k], m);

  float4 bp4 = *(const float4*)bpool;
  float bp[4] = {bp4.x, bp4.y, bp4.z, bp4.w};
  float sv[4][4];
#pragma unroll
  for (int r = 0; r < 4; ++r) {
    float p[4];
#pragma unroll
    for (int k = 0; k < 4; ++k) p[k] = pp[r][k] + bp[k];
    float mx = fmaxf(fmaxf(p[0], p[1]), fmaxf(p[2], p[3]));
    float e0 = expf(p[0] - mx), e1 = expf(p[1] - mx), e2 = expf(p[2] - mx), e3 = expf(p[3] - mx);
    float inv = 1.f / (e0 + e1 + e2 + e3);
    float valid = (g4 * 4 + r < nrows) ? 1.f : 0.f;
    sv[r][0] = e0 * inv * valid; sv[r][1] = e1 * inv * valid;
    sv[r][2] = e2 * inv * valid; sv[r][3] = e3 * inv * valid;
  }

  // write s
  {
    int rW = li >> 2, kW = li & 3;
    if (g4 * 4 + rW < nrows) {
      int node = node0 + g4 * 4 + rW;
      float val = 0.f;
#pragma unroll
      for (int rr = 0; rr < 4; ++rr)
#pragma unroll
        for (int kk = 0; kk < 4; ++kk)
          if (li == rr * 4 + kk) val = sv[rr][kk];
      s_out[node * 4 + kW] = val;
    }
  }

  // ss[b][k1][k2]
  {
    int k1 = li >> 2, k2 = li & 3;
    float a1[4], a2[4];
#pragma unroll
    for (int rr = 0; rr < 4; ++rr) {
      float v1 = 0.f, v2 = 0.f;
#pragma unroll
      for (int kk = 0; kk < 4; ++kk) {
        if (k1 == kk) v1 = sv[rr][kk];
        if (k2 == kk) v2 = sv[rr][kk];
      }
      a1[rr] = v1; a2[rr] = v2;
    }
    float ssv = a1[0] * a2[0] + a1[1] * a2[1] + a1[2] * a2[2] + a1[3] * a2[3];
    atomicAdd(&ssL[li], ssv);
  }

  // den[b] += deg * ||s||^2
  if (li == 0) {
    float dent = 0.f;
#pragma unroll
    for (int rr = 0; rr < 4; ++rr) {
      int rowg = g4 * 4 + rr;
      if (rowg < nrows) {
        float dg = (float)count[node0 + rowg];
        dent += dg * (sv[rr][0] * sv[rr][0] + sv[rr][1] * sv[rr][1] +
                      sv[rr][2] * sv[rr][2] + sv[rr][3] * sv[rr][3]);
      }
    }
    atomicAdd(&denL, dent);
  }

  // out[b][k][c] += s[r][k]*h[r][c]
  float po[4][8];
#pragma unroll
  for (int k = 0; k < 4; ++k)
#pragma unroll
    for (int c = 0; c < 8; ++c) po[k][c] = 0.f;
#pragma unroll
  for (int k = 0; k < 4; ++k)
#pragma unroll
    for (int rr = 0; rr < 4; ++rr)
#pragma unroll
      for (int c = 0; c < 8; ++c) po[k][c] = fmaf(sv[rr][k], h[rr][c], po[k][c]);
#pragma unroll
  for (int k = 0; k < 4; ++k)
#pragma unroll
    for (int c = 0; c < 8; ++c) {
      po[k][c] += __shfl_xor(po[k][c], 16);
      po[k][c] += __shfl_xor(po[k][c], 32);
    }
  if ((t & 63) < 16) {
#pragma unroll
    for (int k = 0; k < 4; ++k)
#pragma unroll
      for (int c = 0; c < 8; ++c)
        atomicAdd(&outL[k][c0 + (c & 3) + (c >> 2) * 64], po[k][c]);
  }

  __syncthreads();
  for (int i = t; i < KC * HID; i += 256)
    atomicAdd(&out_pool[bG * KC * HID + i], ((const float*)outL)[i]);
  if (t < 16) atomicAdd(&ss_g[bG * 16 + t], ssL[t]);
  if (t == 0) atomicAdd(&den_g[bG], denL);
}

// ---------------------------------------------------------------- K4: out_adj[b] = sum_n s[n] (x) t[n],  t[n] = sum_{e: dst=n} s[src]
__global__ __launch_bounds__(256) void k_adj2(const int* __restrict__ count,
                                              const int* __restrict__ rowptr,
                                              const int* __restrict__ csr,
                                              const float* __restrict__ s,
                                              float* __restrict__ adjraw) {
  __shared__ float accL[4][2][16];  // [wave][graph-within-block][k1*4+k2]
  const int t = threadIdx.x;
  if (t < 128) ((float*)accL)[t] = 0.f;
  __syncthreads();
  const int node = blockIdx.x * 256 + t;
  const int g0 = (blockIdx.x * 256) / BLK;
  if (node < NN) {
    const int gi = node / BLK - g0;  // 0 or 1
    const int deg = count[node];
    const int* sl = csr + rowptr[node];
    float t0 = 0.f, t1 = 0.f, t2 = 0.f, t3 = 0.f;
    for (int e = 0; e < deg; ++e) {
      float4 svv = *(const float4*)(s + (size_t)sl[e] * 4);
      t0 += svv.x; t1 += svv.y; t2 += svv.z; t3 += svv.w;
    }
    float4 sn = *(const float4*)(s + (size_t)node * 4);
    float* base = accL[t >> 6][gi];
#pragma unroll
    for (int i = 0; i < 16; ++i) {
      int idx = (i + t) & 15;  // stagger: 4-way instead of 64-way contention
      int hi = idx >> 2, lo = idx & 3;
      float a = (hi == 0) ? sn.x : (hi == 1) ? sn.y : (hi == 2) ? sn.z : sn.w;
      float b = (lo == 0) ? t0 : (lo == 1) ? t1 : (lo == 2) ? t2 : t3;
      atomicAdd(base + idx, a * b);
    }
  }
  __syncthreads();
  if (t < 32) {
    int gi = t >> 4, i = t & 15, gg = g0 + gi;
    if (gg < NB) {
      float v = accL[0][gi][i] + accL[1][gi][i] + accL[2][gi][i] + accL[3][gi][i];
      atomicAdd(&adjraw[gg * 16 + i], v);
    }
  }
}

// ---------------------------------------------------------------- K5a: per-graph tail
__global__ __launch_bounds__(128) void k_graph(
    const float* __restrict__ out_pool, const float* __restrict__ adjraw,
    const float* __restrict__ den_g, const float* __restrict__ ss_g,
    const float* __restrict__ Wrel3, const float* __restrict__ brel3,
    const float* __restrict__ Wroot3, const float* __restrict__ Wlin1,
    const float* __restrict__ blin1, const float* __restrict__ Wlin2,
    const float* __restrict__ blin2, float* __restrict__ d_out,
    float* __restrict__ scratch) {
  const int b = blockIdx.x, t = threadIdx.x;
  __shared__ float adjL[16], adjnL[16], dL[4];
  __shared__ float osL[128], msL[128], x2mL[128], x3L[128];
  if (t < 16) adjL[t] = adjraw[b * 16 + t];
  __syncthreads();
  if (t < 4) {
    float srow = 0.f;
#pragma unroll
    for (int l = 0; l < 4; ++l)
      if (l != t) srow += adjL[t * 4 + l];
    dL[t] = sqrtf(srow) + 1e-15f;
  }
  __syncthreads();
  if (t < 16) {
    int k1 = t >> 2, k2 = t & 3;
    float az = (k1 == k2) ? 0.f : adjL[t];
    float an = az / (dL[k2] * dL[k1]);
    adjnL[t] = an;
    d_out[400018 + b * 16 + t] = an;
  }
  __syncthreads();
  float o0 = out_pool[b * 512 + 0 * 128 + t];
  float o1 = out_pool[b * 512 + 1 * 128 + t];
  float o2 = out_pool[b * 512 + 2 * 128 + t];
  float o3 = out_pool[b * 512 + 3 * 128 + t];
  float m0 = adjnL[0] * o0 + adjnL[1] * o1 + adjnL[2] * o2 + adjnL[3] * o3;
  float m1 = adjnL[4] * o0 + adjnL[5] * o1 + adjnL[6] * o2 + adjnL[7] * o3;
  float m2 = adjnL[8] * o0 + adjnL[9] * o1 + adjnL[10] * o2 + adjnL[11] * o3;
  float m3 = adjnL[12] * o0 + adjnL[13] * o1 + adjnL[14] * o2 + adjnL[15] * o3;
  osL[t] = o0 + o1 + o2 + o3;
  msL[t] = m0 + m1 + m2 + m3;
  __syncthreads();
  float accc = brel3[t];
  for (int j = 0; j < 128; ++j)
    accc += 0.25f * (msL[j] * Wrel3[j * 128 + t] + osL[j] * Wroot3[j * 128 + t]);
  x2mL[t] = accc;
  __syncthreads();
  float a2 = blin1[t];
  for (int j = 0; j < 128; ++j) a2 += x2mL[j] * Wlin1[j * 128 + t];
  x3L[t] = fmaxf(a2, 0.f);
  __syncthreads();
  if (t < 2) {
    float lg = blin2[t];
    for (int j = 0; j < 128; ++j) lg += x3L[j] * Wlin2[j * 2 + t];
    scratch[b * 2 + t] = lg;
  }
  if (t == 0) {
    float tr = adjL[0] + adjL[5] + adjL[10] + adjL[15];
    scratch[16 + b] = tr / den_g[b];
    float n2 = 0.f;
    for (int i = 0; i < 16; ++i) { float v = ss_g[b * 16 + i]; n2 += v * v; }
    float nn = sqrtf(n2);
    float od = 0.f;
    for (int i = 0; i < 16; ++i) {
      float v = ss_g[b * 16 + i] / nn - (((i >> 2) == (i & 3)) ? 0.5f : 0.f);
      od += v * v;
    }
    scratch[24 + b] = sqrtf(od);
  }
}

// ---------------------------------------------------------------- K5b: losses + log_softmax
__global__ void k_final(const float* __restrict__ scratch, float* __restrict__ d_out) {
  if (threadIdx.x == 0 && blockIdx.x == 0) {
    float mc = 0.f, oo = 0.f;
    for (int b = 0; b < NB; ++b) { mc += scratch[16 + b]; oo += scratch[24 + b]; }
    d_out[16] = -(mc / (float)NB);
    d_out[17] = oo / (float)NB;
    for (int b = 0; b < NB; ++b) {
      float l0 = scratch[2 * b], l1 = scratch[2 * b + 1];
      float m = fmaxf(l0, l1);
      float lse = m + logf(expf(l0 - m) + expf(l1 - m));
      d_out[2 * b] = l0 - lse;
      d_out[2 * b + 1] = l1 - lse;
    }
  }
}

// ---------------------------------------------------------------- launch
extern "C" void kernel_launch(void* const* d_in, const int* in_sizes, int n_in,
                              void* d_out, int out_size, void* d_ws, size_t ws_size,
                              hipStream_t stream) {
  (void)in_sizes; (void)n_in; (void)out_size; (void)ws_size;
  const float* x      = (const float*)d_in[0];
  const int*   ei     = (const int*)d_in[1];
  const float* Wroot1 = (const float*)d_in[3];
  const float* Wrel1  = (const float*)d_in[4];
  const float* brel1  = (const float*)d_in[5];
  const float* Wpool  = (const float*)d_in[6];
  const float* bpool  = (const float*)d_in[7];
  const float* Wrel3  = (const float*)d_in[8];
  const float* brel3  = (const float*)d_in[9];
  const float* Wroot3 = (const float*)d_in[10];
  const float* Wlin1  = (const float*)d_in[11];
  const float* blin1  = (const float*)d_in[12];
  const float* Wlin2  = (const float*)d_in[13];
  const float* blin2  = (const float*)d_in[14];
  float* out = (float*)d_out;

  char* ws = (char*)d_ws;
  int*    count    = (int*)(ws + 0);            //   400000 B (memset)
  float*  out_pool = (float*)(ws + 400000);     //    16384 B (memset)
  float*  ss_g     = (float*)(ws + 416384);     //      512 B (memset)
  float*  adjraw   = (float*)(ws + 416896);     //      512 B (memset)
  float*  den_g    = (float*)(ws + 417408);     //       32 B (memset)
  float*  scratch  = (float*)(ws + 417440);     //      128 B (memset)
  int*    rowptr   = (int*)(ws + 417568);       //   400016 B
  int*    cursor   = (int*)(ws + 817584);       //   400016 B
  int*    blocksum = (int*)(ws + 1217600);      //     1024 B
  ushort* Wt       = (ushort*)(ws + 1218624);   //    65536 B [128][256]
  int*    csr      = (int*)(ws + 1284160);      //  6400000 B [E]
  ushort* xb       = (ushort*)(ws + 7684160);   // 25600000 B [N][128] bf16
  ushort* aggb     = (ushort*)(ws + 33284160);  // 25600000 B [N][128] bf16

  hipMemsetAsync(ws, 0, 417568, stream);
  k_prep_x<<<12500, 256, 0, stream>>>((const float4*)x, xb);
  k_prep_w<<<128, 256, 0, stream>>>(Wrel1, Wroot1, Wt);
  k_count<<<(EE + 255) / 256, 256, 0, stream>>>(ei, count);
  k_scanA<<<SCANB, 256, 0, stream>>>(count, blocksum);
  k_scanB<<<1, 256, 0, stream>>>(blocksum);
  k_scanC<<<SCANB, 256, 0, stream>>>(count, blocksum, rowptr, cursor);
  k_fill_g<<<8 * 48, 256, 0, stream>>>(ei, cursor, csr);  // 48 chunks x 8 graphs
  k_agg2<<<8 * ((BLK + 7) / 8), 256, 0, stream>>>(xb, count, rowptr, csr, aggb);
  k_fused<<<NB * CHUNKS, 256, 0, stream>>>(aggb, xb, Wt, brel1, Wpool, bpool, count,
                                           out + 18, out_pool, ss_g, den_g);
  k_adj2<<<(NN + 255) / 256, 256, 0, stream>>>(count, rowptr, csr, out + 18, adjraw);
  k_graph<<<NB, 128, 0, stream>>>(out_pool, adjraw, den_g, ss_g, Wrel3, brel3, Wroot3,
                                  Wlin1, blin1, Wlin2, blin2, out, scratch);
  k_final<<<1, 64, 0, stream>>>(scratch, out);
}

// Round 5
// 341.836 us; speedup vs baseline: 1.0785x; 1.0132x over previous
//
#include <hip/hip_runtime.h>

// Problem constants (fixed by the reference)
#define NN     100000      // nodes
#define EE     1600000     // edges
#define NB     8           // graphs
#define BLK    12500       // nodes per graph
#define HID    128
#define KC     4
#define CHUNKS 196         // ceil(12500/64)
#define SCANB  196         // scan blocks (512 nodes each)
#define FILLC  96          // fill chunks per graph

typedef __attribute__((ext_vector_type(8))) short bf16x8;
typedef __attribute__((ext_vector_type(4))) float f32x4;

__device__ __forceinline__ ushort f2bf(float f) {
  uint u = __float_as_uint(f);
  return (ushort)((u + 0x7FFFu + ((u >> 16) & 1u)) >> 16);  // RNE
}
__device__ __forceinline__ float bf2f(ushort h) {
  return __uint_as_float(((uint)h) << 16);
}

// ---------------------------------------------------------------- K0a: x -> bf16
__global__ __launch_bounds__(256) void k_prep_x(const float4* __restrict__ x4,
                                                ushort* __restrict__ xb) {
  int i = blockIdx.x * 256 + threadIdx.x;  // 3.2M float4s exactly
  float4 v = x4[i];
  ushort4 r;
  r.x = f2bf(v.x); r.y = f2bf(v.y); r.z = f2bf(v.z); r.w = f2bf(v.w);
  *(ushort4*)(xb + (size_t)i * 4) = r;
}

// ---------------------------------------------------------------- K0b: Wt[col][k], k<128 = Wrel1, k>=128 = Wroot1
__global__ __launch_bounds__(256) void k_prep_w(const float* __restrict__ Wrel1,
                                                const float* __restrict__ Wroot1,
                                                ushort* __restrict__ Wt) {
  int col = blockIdx.x, k = threadIdx.x;
  float v = (k < 128) ? Wrel1[k * 128 + col] : Wroot1[(k - 128) * 128 + col];
  Wt[col * 256 + k] = f2bf(v);
}

// ---------------------------------------------------------------- K1a: degree histogram (nt edge read: no reuse)
__global__ __launch_bounds__(256) void k_count(const int* __restrict__ ei,
                                               int* __restrict__ count) {
  int e = blockIdx.x * 256 + threadIdx.x;
  if (e >= EE) return;
  int dst = __builtin_nontemporal_load(ei + EE + e);
  atomicAdd(&count[dst], 1);
}

// ---------------------------------------------------------------- K1b: scan phase A — per-block (512 nodes) sums
__global__ __launch_bounds__(256) void k_scanA(const int* __restrict__ count,
                                               int* __restrict__ blocksum) {
  __shared__ int sd[256];
  const int t = threadIdx.x;
  int i0 = blockIdx.x * 512 + 2 * t;
  int v = 0;
  if (i0 < NN) v += count[i0];
  if (i0 + 1 < NN) v += count[i0 + 1];
  sd[t] = v;
  __syncthreads();
  for (int off = 128; off > 0; off >>= 1) {
    if (t < off) sd[t] += sd[t + off];
    __syncthreads();
  }
  if (t == 0) blocksum[blockIdx.x] = sd[0];
}

// ---------------------------------------------------------------- K1c: scan phase B — exclusive scan of block sums
__global__ __launch_bounds__(256) void k_scanB(int* __restrict__ blocksum) {
  __shared__ int sd[256];
  const int t = threadIdx.x;
  int v = (t < SCANB) ? blocksum[t] : 0;
  sd[t] = v;
  __syncthreads();
  for (int off = 1; off < 256; off <<= 1) {
    int x = (t >= off) ? sd[t - off] : 0;
    __syncthreads();
    sd[t] += x;
    __syncthreads();
  }
  if (t < SCANB) blocksum[t] = sd[t] - v;  // exclusive
}

// ---------------------------------------------------------------- K1d: scan phase C — rowptr + cursor
__global__ __launch_bounds__(256) void k_scanC(const int* __restrict__ count,
                                               const int* __restrict__ blocksum,
                                               int* __restrict__ rowptr,
                                               int* __restrict__ cursor) {
  __shared__ int sd[256];
  const int t = threadIdx.x;
  const int base = blocksum[blockIdx.x];
  int i0 = blockIdx.x * 512 + 2 * t;
  int c0 = (i0 < NN) ? count[i0] : 0;
  int c1 = (i0 + 1 < NN) ? count[i0 + 1] : 0;
  int v = c0 + c1;
  sd[t] = v;
  __syncthreads();
  for (int off = 1; off < 256; off <<= 1) {
    int x = (t >= off) ? sd[t - off] : 0;
    __syncthreads();
    sd[t] += x;
    __syncthreads();
  }
  int excl = base + sd[t] - v;
  if (i0 < NN) { rowptr[i0] = excl; cursor[i0] = excl; }
  if (i0 + 1 < NN) { rowptr[i0 + 1] = excl + c0; cursor[i0 + 1] = excl + c0; }
}

// ---------------------------------------------------------------- K1e: fill CSR, XCD-local by graph + NT edge stream
// Block b handles ONLY graph b%8's edges (blockIdx%8 -> XCD round-robin), so
// the scattered csr/cursor writes for one graph (~850 KB) stay in one XCD's
// 4 MB L2. The edge-list scan is NON-TEMPORAL so the 12.8 MB stream does not
// evict those dirty lines (R4 showed stream-eviction caused 10x write
// amplification). Perf heuristic only: correctness is mapping-independent.
__global__ __launch_bounds__(256) void k_fill_g(const int* __restrict__ ei,
                                                int* __restrict__ cursor,
                                                int* __restrict__ csr) {
  const int g = blockIdx.x & 7;
  const int chunk = blockIdx.x >> 3;
  const int lo = g * BLK, hi = lo + BLK;
  const int per = (EE + FILLC - 1) / FILLC;
  const int e0 = chunk * per;
  int e1 = e0 + per;
  if (e1 > EE) e1 = EE;
  for (int e = e0 + threadIdx.x; e < e1; e += 256) {
    int dst = __builtin_nontemporal_load(ei + EE + e);
    if (dst >= lo && dst < hi) {
      int src = __builtin_nontemporal_load(ei + e);
      int pos = atomicAdd(&cursor[dst], 1);
      csr[pos] = src;
    }
  }
}

// ---------------------------------------------------------------- K2: agg[n] = sum_{e: dst=n} x[src]  (bf16, fp32 accum)
// XCD-aware: blockIdx%8 selects the graph so each XCD's L2 holds one graph's
// 3.2 MB x-slice.
__global__ __launch_bounds__(256) void k_agg2(const ushort* __restrict__ xb,
                                              const int* __restrict__ count,
                                              const int* __restrict__ rowptr,
                                              const int* __restrict__ csr,
                                              ushort* __restrict__ aggb) {
  const int xg = blockIdx.x & 7;
  const int j = blockIdx.x >> 3;
  const int half = threadIdx.x >> 5;  // 8 half-waves = 8 nodes per block
  const int lane = threadIdx.x & 31;
  const int ln = j * 8 + half;
  if (ln >= BLK) return;
  const int node = xg * BLK + ln;
  const int deg = count[node];
  const int* sl = csr + rowptr[node];
  int idx0 = (lane < deg) ? sl[lane] : 0;
  int idx1 = (32 + lane < deg) ? sl[32 + lane] : 0;
  float a0 = 0.f, a1 = 0.f, a2 = 0.f, a3 = 0.f;
  for (int e = 0; e < deg; ++e) {
    int srcn = (e < 32) ? __shfl(idx0, e, 32)
                        : ((e < 64) ? __shfl(idx1, e - 32, 32) : sl[e]);
    ushort4 v = *(const ushort4*)(xb + (size_t)srcn * HID + lane * 4);
    a0 += bf2f(v.x); a1 += bf2f(v.y); a2 += bf2f(v.z); a3 += bf2f(v.w);
  }
  ushort4 r;
  r.x = f2bf(a0); r.y = f2bf(a1); r.z = f2bf(a2); r.w = f2bf(a3);
  *(ushort4*)(aggb + (size_t)node * HID + lane * 4) = r;
}

// ---------------------------------------------------------------- K3: MFMA GEMM + softmax + pooled reductions
__global__ __launch_bounds__(256) void k_fused(
    const ushort* __restrict__ aggb, const ushort* __restrict__ xb,
    const ushort* __restrict__ Wt, const float* __restrict__ brel1,
    const float* __restrict__ Wpool, const float* __restrict__ bpool,
    const int* __restrict__ count, float* __restrict__ s_out,
    float* __restrict__ out_pool, float* __restrict__ ss_g,
    float* __restrict__ den_g) {
  __shared__ ushort As[64][40];    // 64 rows x 32 k (pad->40)
  __shared__ ushort Bs[128][40];   // 128 cols x 32 k
  __shared__ float hL[64][132];    // h tile (pad 128->132)
  __shared__ float outL[KC][HID];
  __shared__ float ssL[16];
  __shared__ float denL;

  const int t = threadIdx.x;
  const int bG = blockIdx.x / CHUNKS;
  const int chunk = blockIdx.x % CHUNKS;
  const int node0 = bG * BLK + chunk * 64;
  int nrows = BLK - chunk * 64;
  if (nrows > 64) nrows = 64;

  for (int i = t; i < KC * HID; i += 256) ((float*)outL)[i] = 0.f;
  if (t < 16) ssL[t] = 0.f;
  if (t == 0) denL = 0.f;

  const int w = t >> 6;     // wave: cols 32w..32w+31
  const int l = t & 63;
  const int m16 = l & 15;
  const int gq = l >> 4;

  f32x4 acc[4][2];
#pragma unroll
  for (int fr = 0; fr < 4; ++fr)
#pragma unroll
    for (int fc = 0; fc < 2; ++fc) acc[fr][fc] = (f32x4){0.f, 0.f, 0.f, 0.f};

  const int arow = t >> 2;
  const int acol = (t & 3) * 8;
  const int arr = (arow < nrows) ? arow : (nrows - 1);
  const ushort* Aag = aggb + (size_t)(node0 + arr) * HID + acol;
  const ushort* Axx = xb + (size_t)(node0 + arr) * HID + acol;

#pragma unroll 1
  for (int kt = 0; kt < 8; ++kt) {
    const int kb = (kt & 3) * 32;
    __syncthreads();
    {
      const ushort* srcp = (kt < 4) ? (Aag + kb) : (Axx + kb);
      *(uint4*)&As[arow][acol] = *(const uint4*)srcp;
#pragma unroll
      for (int i = 0; i < 2; ++i) {
        int idx = i * 256 + t;
        int col = idx >> 2, ch = (idx & 3) * 8;
        *(uint4*)&Bs[col][ch] = *(const uint4*)(Wt + (size_t)col * 256 + kt * 32 + ch);
      }
    }
    __syncthreads();
    bf16x8 af[4], bfr[2];
#pragma unroll
    for (int fr = 0; fr < 4; ++fr)
      af[fr] = *(const bf16x8*)&As[16 * fr + m16][8 * gq];
#pragma unroll
    for (int fc = 0; fc < 2; ++fc)
      bfr[fc] = *(const bf16x8*)&Bs[32 * w + 16 * fc + m16][8 * gq];
#pragma unroll
    for (int fr = 0; fr < 4; ++fr)
#pragma unroll
      for (int fc = 0; fc < 2; ++fc)
        acc[fr][fc] = __builtin_amdgcn_mfma_f32_16x16x32_bf16(af[fr], bfr[fc],
                                                              acc[fr][fc], 0, 0, 0);
  }

  // bias + relu -> hL  (D layout: row = 4*(l>>4)+reg, col = l&15  [m89])
  const float bc0 = brel1[32 * w + m16];
  const float bc1 = brel1[32 * w + 16 + m16];
#pragma unroll
  for (int fr = 0; fr < 4; ++fr)
#pragma unroll
    for (int fc = 0; fc < 2; ++fc)
#pragma unroll
      for (int r = 0; r < 4; ++r)
        hL[16 * fr + 4 * gq + r][32 * w + 16 * fc + m16] =
            fmaxf(acc[fr][fc][r] + (fc ? bc1 : bc0), 0.f);
  __syncthreads();

  // ---- epilogue (16-lane groups own 4 rows each) ----
  const int g4 = t >> 4;
  const int c0 = (t & 15) << 2;
  const int li = t & 15;

  float h[4][8];
#pragma unroll
  for (int r = 0; r < 4; ++r) {
    float4 v0 = *(const float4*)&hL[g4 * 4 + r][c0];
    float4 v1 = *(const float4*)&hL[g4 * 4 + r][c0 + 64];
    h[r][0] = v0.x; h[r][1] = v0.y; h[r][2] = v0.z; h[r][3] = v0.w;
    h[r][4] = v1.x; h[r][5] = v1.y; h[r][6] = v1.z; h[r][7] = v1.w;
  }

  // pooling head: p = h @ Wpool
  float wp[8][4];
#pragma unroll
  for (int j = 0; j < 8; ++j) {
    int col = c0 + (j & 3) + (j >> 2) * 64;
    float4 v = *(const float4*)(Wpool + col * 4);
    wp[j][0] = v.x; wp[j][1] = v.y; wp[j][2] = v.z; wp[j][3] = v.w;
  }
  float pp[4][4];
#pragma unroll
  for (int r = 0; r < 4; ++r)
#pragma unroll
    for (int k = 0; k < 4; ++k) pp[r][k] = 0.f;
#pragma unroll
  for (int r = 0; r < 4; ++r)
#pragma unroll
    for (int j = 0; j < 8; ++j)
#pragma unroll
      for (int k = 0; k < 4; ++k) pp[r][k] = fmaf(h[r][j], wp[j][k], pp[r][k]);
#pragma unroll
  for (int m = 1; m <= 8; m <<= 1)
#pragma unroll
    for (int r = 0; r < 4; ++r)
#pragma unroll
      for (int k = 0; k < 4; ++k) pp[r][k] += __shfl_xor(pp[r][k], m);

  float4 bp4 = *(const float4*)bpool;
  float bp[4] = {bp4.x, bp4.y, bp4.z, bp4.w};
  float sv[4][4];
#pragma unroll
  for (int r = 0; r < 4; ++r) {
    float p[4];
#pragma unroll
    for (int k = 0; k < 4; ++k) p[k] = pp[r][k] + bp[k];
    float mx = fmaxf(fmaxf(p[0], p[1]), fmaxf(p[2], p[3]));
    float e0 = expf(p[0] - mx), e1 = expf(p[1] - mx), e2 = expf(p[2] - mx), e3 = expf(p[3] - mx);
    float inv = 1.f / (e0 + e1 + e2 + e3);
    float valid = (g4 * 4 + r < nrows) ? 1.f : 0.f;
    sv[r][0] = e0 * inv * valid; sv[r][1] = e1 * inv * valid;
    sv[r][2] = e2 * inv * valid; sv[r][3] = e3 * inv * valid;
  }

  // write s
  {
    int rW = li >> 2, kW = li & 3;
    if (g4 * 4 + rW < nrows) {
      int node = node0 + g4 * 4 + rW;
      float val = 0.f;
#pragma unroll
      for (int rr = 0; rr < 4; ++rr)
#pragma unroll
        for (int kk = 0; kk < 4; ++kk)
          if (li == rr * 4 + kk) val = sv[rr][kk];
      s_out[node * 4 + kW] = val;
    }
  }

  // ss[b][k1][k2]
  {
    int k1 = li >> 2, k2 = li & 3;
    float a1[4], a2[4];
#pragma unroll
    for (int rr = 0; rr < 4; ++rr) {
      float v1 = 0.f, v2 = 0.f;
#pragma unroll
      for (int kk = 0; kk < 4; ++kk) {
        if (k1 == kk) v1 = sv[rr][kk];
        if (k2 == kk) v2 = sv[rr][kk];
      }
      a1[rr] = v1; a2[rr] = v2;
    }
    float ssv = a1[0] * a2[0] + a1[1] * a2[1] + a1[2] * a2[2] + a1[3] * a2[3];
    atomicAdd(&ssL[li], ssv);
  }

  // den[b] += deg * ||s||^2
  if (li == 0) {
    float dent = 0.f;
#pragma unroll
    for (int rr = 0; rr < 4; ++rr) {
      int rowg = g4 * 4 + rr;
      if (rowg < nrows) {
        float dg = (float)count[node0 + rowg];
        dent += dg * (sv[rr][0] * sv[rr][0] + sv[rr][1] * sv[rr][1] +
                      sv[rr][2] * sv[rr][2] + sv[rr][3] * sv[rr][3]);
      }
    }
    atomicAdd(&denL, dent);
  }

  // out[b][k][c] += s[r][k]*h[r][c]
  float po[4][8];
#pragma unroll
  for (int k = 0; k < 4; ++k)
#pragma unroll
    for (int c = 0; c < 8; ++c) po[k][c] = 0.f;
#pragma unroll
  for (int k = 0; k < 4; ++k)
#pragma unroll
    for (int rr = 0; rr < 4; ++rr)
#pragma unroll
      for (int c = 0; c < 8; ++c) po[k][c] = fmaf(sv[rr][k], h[rr][c], po[k][c]);
#pragma unroll
  for (int k = 0; k < 4; ++k)
#pragma unroll
    for (int c = 0; c < 8; ++c) {
      po[k][c] += __shfl_xor(po[k][c], 16);
      po[k][c] += __shfl_xor(po[k][c], 32);
    }
  if ((t & 63) < 16) {
#pragma unroll
    for (int k = 0; k < 4; ++k)
#pragma unroll
      for (int c = 0; c < 8; ++c)
        atomicAdd(&outL[k][c0 + (c & 3) + (c >> 2) * 64], po[k][c]);
  }

  __syncthreads();
  for (int i = t; i < KC * HID; i += 256)
    atomicAdd(&out_pool[bG * KC * HID + i], ((const float*)outL)[i]);
  if (t < 16) atomicAdd(&ss_g[bG * 16 + t], ssL[t]);
  if (t == 0) atomicAdd(&den_g[bG], denL);
}

// ---------------------------------------------------------------- K4: out_adj[b] = sum_n s[n] (x) t[n],  t[n] = sum_{e: dst=n} s[src]
__global__ __launch_bounds__(256) void k_adj2(const int* __restrict__ count,
                                              const int* __restrict__ rowptr,
                                              const int* __restrict__ csr,
                                              const float* __restrict__ s,
                                              float* __restrict__ adjraw) {
  __shared__ float accL[4][2][16];  // [wave][graph-within-block][k1*4+k2]
  const int t = threadIdx.x;
  if (t < 128) ((float*)accL)[t] = 0.f;
  __syncthreads();
  const int node = blockIdx.x * 256 + t;
  const int g0 = (blockIdx.x * 256) / BLK;
  if (node < NN) {
    const int gi = node / BLK - g0;  // 0 or 1
    const int deg = count[node];
    const int* sl = csr + rowptr[node];
    float t0 = 0.f, t1 = 0.f, t2 = 0.f, t3 = 0.f;
    for (int e = 0; e < deg; ++e) {
      float4 svv = *(const float4*)(s + (size_t)sl[e] * 4);
      t0 += svv.x; t1 += svv.y; t2 += svv.z; t3 += svv.w;
    }
    float4 sn = *(const float4*)(s + (size_t)node * 4);
    float* base = accL[t >> 6][gi];
#pragma unroll
    for (int i = 0; i < 16; ++i) {
      int idx = (i + t) & 15;  // stagger: 4-way instead of 64-way contention
      int hi = idx >> 2, lo = idx & 3;
      float a = (hi == 0) ? sn.x : (hi == 1) ? sn.y : (hi == 2) ? sn.z : sn.w;
      float b = (lo == 0) ? t0 : (lo == 1) ? t1 : (lo == 2) ? t2 : t3;
      atomicAdd(base + idx, a * b);
    }
  }
  __syncthreads();
  if (t < 32) {
    int gi = t >> 4, i = t & 15, gg = g0 + gi;
    if (gg < NB) {
      float v = accL[0][gi][i] + accL[1][gi][i] + accL[2][gi][i] + accL[3][gi][i];
      atomicAdd(&adjraw[gg * 16 + i], v);
    }
  }
}

// ---------------------------------------------------------------- K5a: per-graph tail
__global__ __launch_bounds__(128) void k_graph(
    const float* __restrict__ out_pool, const float* __restrict__ adjraw,
    const float* __restrict__ den_g, const float* __restrict__ ss_g,
    const float* __restrict__ Wrel3, const float* __restrict__ brel3,
    const float* __restrict__ Wroot3, const float* __restrict__ Wlin1,
    const float* __restrict__ blin1, const float* __restrict__ Wlin2,
    const float* __restrict__ blin2, float* __restrict__ d_out,
    float* __restrict__ scratch) {
  const int b = blockIdx.x, t = threadIdx.x;
  __shared__ float adjL[16], adjnL[16], dL[4];
  __shared__ float osL[128], msL[128], x2mL[128], x3L[128];
  if (t < 16) adjL[t] = adjraw[b * 16 + t];
  __syncthreads();
  if (t < 4) {
    float srow = 0.f;
#pragma unroll
    for (int l = 0; l < 4; ++l)
      if (l != t) srow += adjL[t * 4 + l];
    dL[t] = sqrtf(srow) + 1e-15f;
  }
  __syncthreads();
  if (t < 16) {
    int k1 = t >> 2, k2 = t & 3;
    float az = (k1 == k2) ? 0.f : adjL[t];
    float an = az / (dL[k2] * dL[k1]);
    adjnL[t] = an;
    d_out[400018 + b * 16 + t] = an;
  }
  __syncthreads();
  float o0 = out_pool[b * 512 + 0 * 128 + t];
  float o1 = out_pool[b * 512 + 1 * 128 + t];
  float o2 = out_pool[b * 512 + 2 * 128 + t];
  float o3 = out_pool[b * 512 + 3 * 128 + t];
  float m0 = adjnL[0] * o0 + adjnL[1] * o1 + adjnL[2] * o2 + adjnL[3] * o3;
  float m1 = adjnL[4] * o0 + adjnL[5] * o1 + adjnL[6] * o2 + adjnL[7] * o3;
  float m2 = adjnL[8] * o0 + adjnL[9] * o1 + adjnL[10] * o2 + adjnL[11] * o3;
  float m3 = adjnL[12] * o0 + adjnL[13] * o1 + adjnL[14] * o2 + adjnL[15] * o3;
  osL[t] = o0 + o1 + o2 + o3;
  msL[t] = m0 + m1 + m2 + m3;
  __syncthreads();
  float accc = brel3[t];
  for (int j = 0; j < 128; ++j)
    accc += 0.25f * (msL[j] * Wrel3[j * 128 + t] + osL[j] * Wroot3[j * 128 + t]);
  x2mL[t] = accc;
  __syncthreads();
  float a2 = blin1[t];
  for (int j = 0; j < 128; ++j) a2 += x2mL[j] * Wlin1[j * 128 + t];
  x3L[t] = fmaxf(a2, 0.f);
  __syncthreads();
  if (t < 2) {
    float lg = blin2[t];
    for (int j = 0; j < 128; ++j) lg += x3L[j] * Wlin2[j * 2 + t];
    scratch[b * 2 + t] = lg;
  }
  if (t == 0) {
    float tr = adjL[0] + adjL[5] + adjL[10] + adjL[15];
    scratch[16 + b] = tr / den_g[b];
    float n2 = 0.f;
    for (int i = 0; i < 16; ++i) { float v = ss_g[b * 16 + i]; n2 += v * v; }
    float nn = sqrtf(n2);
    float od = 0.f;
    for (int i = 0; i < 16; ++i) {
      float v = ss_g[b * 16 + i] / nn - (((i >> 2) == (i & 3)) ? 0.5f : 0.f);
      od += v * v;
    }
    scratch[24 + b] = sqrtf(od);
  }
}

// ---------------------------------------------------------------- K5b: losses + log_softmax
__global__ void k_final(const float* __restrict__ scratch, float* __restrict__ d_out) {
  if (threadIdx.x == 0 && blockIdx.x == 0) {
    float mc = 0.f, oo = 0.f;
    for (int b = 0; b < NB; ++b) { mc += scratch[16 + b]; oo += scratch[24 + b]; }
    d_out[16] = -(mc / (float)NB);
    d_out[17] = oo / (float)NB;
    for (int b = 0; b < NB; ++b) {
      float l0 = scratch[2 * b], l1 = scratch[2 * b + 1];
      float m = fmaxf(l0, l1);
      float lse = m + logf(expf(l0 - m) + expf(l1 - m));
      d_out[2 * b] = l0 - lse;
      d_out[2 * b + 1] = l1 - lse;
    }
  }
}

// ---------------------------------------------------------------- launch
extern "C" void kernel_launch(void* const* d_in, const int* in_sizes, int n_in,
                              void* d_out, int out_size, void* d_ws, size_t ws_size,
                              hipStream_t stream) {
  (void)in_sizes; (void)n_in; (void)out_size; (void)ws_size;
  const float* x      = (const float*)d_in[0];
  const int*   ei     = (const int*)d_in[1];
  const float* Wroot1 = (const float*)d_in[3];
  const float* Wrel1  = (const float*)d_in[4];
  const float* brel1  = (const float*)d_in[5];
  const float* Wpool  = (const float*)d_in[6];
  const float* bpool  = (const float*)d_in[7];
  const float* Wrel3  = (const float*)d_in[8];
  const float* brel3  = (const float*)d_in[9];
  const float* Wroot3 = (const float*)d_in[10];
  const float* Wlin1  = (const float*)d_in[11];
  const float* blin1  = (const float*)d_in[12];
  const float* Wlin2  = (const float*)d_in[13];
  const float* blin2  = (const float*)d_in[14];
  float* out = (float*)d_out;

  char* ws = (char*)d_ws;
  int*    count    = (int*)(ws + 0);            //   400000 B (memset)
  float*  out_pool = (float*)(ws + 400000);     //    16384 B (memset)
  float*  ss_g     = (float*)(ws + 416384);     //      512 B (memset)
  float*  adjraw   = (float*)(ws + 416896);     //      512 B (memset)
  float*  den_g    = (float*)(ws + 417408);     //       32 B (memset)
  float*  scratch  = (float*)(ws + 417440);     //      128 B (memset)
  int*    rowptr   = (int*)(ws + 417568);       //   400016 B
  int*    cursor   = (int*)(ws + 817584);       //   400016 B
  int*    blocksum = (int*)(ws + 1217600);      //     1024 B
  ushort* Wt       = (ushort*)(ws + 1218624);   //    65536 B [128][256]
  int*    csr      = (int*)(ws + 1284160);      //  6400000 B [E]
  ushort* xb       = (ushort*)(ws + 7684160);   // 25600000 B [N][128] bf16
  ushort* aggb     = (ushort*)(ws + 33284160);  // 25600000 B [N][128] bf16

  hipMemsetAsync(ws, 0, 417568, stream);
  k_prep_x<<<12500, 256, 0, stream>>>((const float4*)x, xb);
  k_prep_w<<<128, 256, 0, stream>>>(Wrel1, Wroot1, Wt);
  k_count<<<(EE + 255) / 256, 256, 0, stream>>>(ei, count);
  k_scanA<<<SCANB, 256, 0, stream>>>(count, blocksum);
  k_scanB<<<1, 256, 0, stream>>>(blocksum);
  k_scanC<<<SCANB, 256, 0, stream>>>(count, blocksum, rowptr, cursor);
  k_fill_g<<<8 * FILLC, 256, 0, stream>>>(ei, cursor, csr);
  k_agg2<<<8 * ((BLK + 7) / 8), 256, 0, stream>>>(xb, count, rowptr, csr, aggb);
  k_fused<<<NB * CHUNKS, 256, 0, stream>>>(aggb, xb, Wt, brel1, Wpool, bpool, count,
                                           out + 18, out_pool, ss_g, den_g);
  k_adj2<<<(NN + 255) / 256, 256, 0, stream>>>(count, rowptr, csr, out + 18, adjraw);
  k_graph<<<NB, 128, 0, stream>>>(out_pool, adjraw, den_g, ss_g, Wrel3, brel3, Wroot3,
                                  Wlin1, blin1, Wlin2, blin2, out, scratch);
  k_final<<<1, 64, 0, stream>>>(scratch, out);
}

// Round 6
// 328.929 us; speedup vs baseline: 1.1208x; 1.0392x over previous
//
#include <hip/hip_runtime.h>

// Problem constants (fixed by the reference)
#define NN     100000      // nodes
#define EE     1600000     // edges
#define NB     8           // graphs
#define BLK    12500       // nodes per graph
#define HID    128
#define KC     4
#define CHUNKS 196         // ceil(12500/64)
#define SCANB  196         // scan blocks (512 nodes each)
#define GCAP   262144      // bucket capacity per graph (mean 200K, sigma ~420)

typedef __attribute__((ext_vector_type(8))) short bf16x8;
typedef __attribute__((ext_vector_type(4))) float f32x4;

__device__ __forceinline__ ushort f2bf(float f) {
  uint u = __float_as_uint(f);
  return (ushort)((u + 0x7FFFu + ((u >> 16) & 1u)) >> 16);  // RNE
}
__device__ __forceinline__ float bf2f(ushort h) {
  return __uint_as_float(((uint)h) << 16);
}

// ---------------------------------------------------------------- K0a: x -> bf16
__global__ __launch_bounds__(256) void k_prep_x(const float4* __restrict__ x4,
                                                ushort* __restrict__ xb) {
  int i = blockIdx.x * 256 + threadIdx.x;  // 3.2M float4s exactly
  float4 v = x4[i];
  ushort4 r;
  r.x = f2bf(v.x); r.y = f2bf(v.y); r.z = f2bf(v.z); r.w = f2bf(v.w);
  *(ushort4*)(xb + (size_t)i * 4) = r;
}

// ---------------------------------------------------------------- K0b: Wt[col][k], k<128 = Wrel1, k>=128 = Wroot1
__global__ __launch_bounds__(256) void k_prep_w(const float* __restrict__ Wrel1,
                                                const float* __restrict__ Wroot1,
                                                ushort* __restrict__ Wt) {
  int col = blockIdx.x, k = threadIdx.x;
  float v = (k < 128) ? Wrel1[k * 128 + col] : Wroot1[(k - 128) * 128 + col];
  Wt[col * 256 + k] = f2bf(v);
}

// ---------------------------------------------------------------- K1a: bucket edges by graph (single coalesced edge-list pass)
// Packed entry: (src_local << 16) | dst_local  (both < 12500 < 2^16).
// Block-local LDS staging + one global cursor reservation per graph makes
// the bucket writes contiguous dense lines (~6.4 MB total, written once).
__global__ __launch_bounds__(256) void k_bucket(const int* __restrict__ ei,
                                                int* __restrict__ gcur,
                                                uint* __restrict__ gbuf) {
  __shared__ uint stage[2048];
  __shared__ int cnt[8], start[9], base[8], pos[8];
  const int t = threadIdx.x;
  if (t < 8) { cnt[t] = 0; pos[t] = 0; }
  __syncthreads();
  const int e0 = blockIdx.x * 2048;
  uint pk[8]; int gg[8]; bool val[8];
#pragma unroll
  for (int i = 0; i < 8; ++i) {
    int e = e0 + i * 256 + t;
    val[i] = (e < EE);
    int src = 0, dst = 0;
    if (val[i]) {
      src = __builtin_nontemporal_load(ei + e);
      dst = __builtin_nontemporal_load(ei + EE + e);
    }
    int g = dst / BLK;
    gg[i] = g;
    pk[i] = ((uint)(src - g * BLK) << 16) | (uint)(dst - g * BLK);
    if (val[i]) atomicAdd(&cnt[g], 1);
  }
  __syncthreads();
  if (t == 0) {
    int s = 0;
#pragma unroll
    for (int g = 0; g < 8; ++g) { start[g] = s; s += cnt[g]; }
    start[8] = s;
  }
  __syncthreads();
  if (t < 8) base[t] = atomicAdd(&gcur[t], cnt[t]);
#pragma unroll
  for (int i = 0; i < 8; ++i) {
    if (val[i]) {
      int off = atomicAdd(&pos[gg[i]], 1);
      stage[start[gg[i]] + off] = pk[i];
    }
  }
  __syncthreads();
  const int total = start[8];
  for (int i = t; i < total; i += 256) {
    int g = 0;
#pragma unroll
    for (int q = 1; q < 8; ++q) if (i >= start[q]) g = q;
    gbuf[(size_t)g * GCAP + base[g] + (i - start[g])] = stage[i];
  }
}

// ---------------------------------------------------------------- K1b: degree histogram from buckets (graph-per-XCD)
__global__ __launch_bounds__(256) void k_count_b(const uint* __restrict__ gbuf,
                                                 const int* __restrict__ gcur,
                                                 int* __restrict__ count) {
  const int g = blockIdx.x & 7;
  const int chunk = blockIdx.x >> 3;
  const int nch = gridDim.x >> 3;
  const int n = gcur[g];
  const int per = (n + nch - 1) / nch;
  int i0 = chunk * per, i1 = i0 + per;
  if (i1 > n) i1 = n;
  const uint* buf = gbuf + (size_t)g * GCAP;
  for (int i = i0 + threadIdx.x; i < i1; i += 256)
    atomicAdd(&count[g * BLK + (int)(buf[i] & 0xFFFFu)], 1);
}

// ---------------------------------------------------------------- K1c: scan phase A — per-block (512 nodes) sums
__global__ __launch_bounds__(256) void k_scanA(const int* __restrict__ count,
                                               int* __restrict__ blocksum) {
  __shared__ int sd[256];
  const int t = threadIdx.x;
  int i0 = blockIdx.x * 512 + 2 * t;
  int v = 0;
  if (i0 < NN) v += count[i0];
  if (i0 + 1 < NN) v += count[i0 + 1];
  sd[t] = v;
  __syncthreads();
  for (int off = 128; off > 0; off >>= 1) {
    if (t < off) sd[t] += sd[t + off];
    __syncthreads();
  }
  if (t == 0) blocksum[blockIdx.x] = sd[0];
}

// ---------------------------------------------------------------- K1d: scan phase B — exclusive scan of block sums
__global__ __launch_bounds__(256) void k_scanB(int* __restrict__ blocksum) {
  __shared__ int sd[256];
  const int t = threadIdx.x;
  int v = (t < SCANB) ? blocksum[t] : 0;
  sd[t] = v;
  __syncthreads();
  for (int off = 1; off < 256; off <<= 1) {
    int x = (t >= off) ? sd[t - off] : 0;
    __syncthreads();
    sd[t] += x;
    __syncthreads();
  }
  if (t < SCANB) blocksum[t] = sd[t] - v;  // exclusive
}

// ---------------------------------------------------------------- K1e: scan phase C — rowptr + cursor
__global__ __launch_bounds__(256) void k_scanC(const int* __restrict__ count,
                                               const int* __restrict__ blocksum,
                                               int* __restrict__ rowptr,
                                               int* __restrict__ cursor) {
  __shared__ int sd[256];
  const int t = threadIdx.x;
  const int base = blocksum[blockIdx.x];
  int i0 = blockIdx.x * 512 + 2 * t;
  int c0 = (i0 < NN) ? count[i0] : 0;
  int c1 = (i0 + 1 < NN) ? count[i0 + 1] : 0;
  int v = c0 + c1;
  sd[t] = v;
  __syncthreads();
  for (int off = 1; off < 256; off <<= 1) {
    int x = (t >= off) ? sd[t - off] : 0;
    __syncthreads();
    sd[t] += x;
    __syncthreads();
  }
  int excl = base + sd[t] - v;
  if (i0 < NN) { rowptr[i0] = excl; cursor[i0] = excl; }
  if (i0 + 1 < NN) { rowptr[i0 + 1] = excl + c0; cursor[i0 + 1] = excl + c0; }
}

// ---------------------------------------------------------------- K1f: fill CSR from buckets (graph-per-XCD)
// XCD g touches only: its 800 KB bucket (read), its ~850 KB csr/cursor
// slices (write) -> total < 2 MB, fully L2-resident, line-dense write-back.
__global__ __launch_bounds__(256) void k_fill_b(const uint* __restrict__ gbuf,
                                                const int* __restrict__ gcur,
                                                int* __restrict__ cursor,
                                                int* __restrict__ csr) {
  const int g = blockIdx.x & 7;
  const int chunk = blockIdx.x >> 3;
  const int nch = gridDim.x >> 3;
  const int n = gcur[g];
  const int per = (n + nch - 1) / nch;
  int i0 = chunk * per, i1 = i0 + per;
  if (i1 > n) i1 = n;
  const uint* buf = gbuf + (size_t)g * GCAP;
  const int nb = g * BLK;
  for (int i = i0 + threadIdx.x; i < i1; i += 256) {
    uint pk = buf[i];
    int dst = nb + (int)(pk & 0xFFFFu);
    int src = nb + (int)(pk >> 16);
    int pos = atomicAdd(&cursor[dst], 1);
    csr[pos] = src;
  }
}

// ---------------------------------------------------------------- K2: agg[n] = sum_{e: dst=n} x[src]  (bf16, fp32 accum)
// XCD-aware: blockIdx%8 selects the graph so each XCD's L2 holds one graph's
// 3.2 MB x-slice.
__global__ __launch_bounds__(256) void k_agg2(const ushort* __restrict__ xb,
                                              const int* __restrict__ count,
                                              const int* __restrict__ rowptr,
                                              const int* __restrict__ csr,
                                              ushort* __restrict__ aggb) {
  const int xg = blockIdx.x & 7;
  const int j = blockIdx.x >> 3;
  const int half = threadIdx.x >> 5;  // 8 half-waves = 8 nodes per block
  const int lane = threadIdx.x & 31;
  const int ln = j * 8 + half;
  if (ln >= BLK) return;
  const int node = xg * BLK + ln;
  const int deg = count[node];
  const int* sl = csr + rowptr[node];
  int idx0 = (lane < deg) ? sl[lane] : 0;
  int idx1 = (32 + lane < deg) ? sl[32 + lane] : 0;
  float a0 = 0.f, a1 = 0.f, a2 = 0.f, a3 = 0.f;
  for (int e = 0; e < deg; ++e) {
    int srcn = (e < 32) ? __shfl(idx0, e, 32)
                        : ((e < 64) ? __shfl(idx1, e - 32, 32) : sl[e]);
    ushort4 v = *(const ushort4*)(xb + (size_t)srcn * HID + lane * 4);
    a0 += bf2f(v.x); a1 += bf2f(v.y); a2 += bf2f(v.z); a3 += bf2f(v.w);
  }
  ushort4 r;
  r.x = f2bf(a0); r.y = f2bf(a1); r.z = f2bf(a2); r.w = f2bf(a3);
  *(ushort4*)(aggb + (size_t)node * HID + lane * 4) = r;
}

// ---------------------------------------------------------------- K3: MFMA GEMM + softmax + pooled reductions
__global__ __launch_bounds__(256) void k_fused(
    const ushort* __restrict__ aggb, const ushort* __restrict__ xb,
    const ushort* __restrict__ Wt, const float* __restrict__ brel1,
    const float* __restrict__ Wpool, const float* __restrict__ bpool,
    const int* __restrict__ count, float* __restrict__ s_out,
    float* __restrict__ out_pool, float* __restrict__ ss_g,
    float* __restrict__ den_g) {
  __shared__ ushort As[64][40];    // 64 rows x 32 k (pad->40)
  __shared__ ushort Bs[128][40];   // 128 cols x 32 k
  __shared__ float hL[64][132];    // h tile (pad 128->132)
  __shared__ float outL[KC][HID];
  __shared__ float ssL[16];
  __shared__ float denL;

  const int t = threadIdx.x;
  const int bG = blockIdx.x / CHUNKS;
  const int chunk = blockIdx.x % CHUNKS;
  const int node0 = bG * BLK + chunk * 64;
  int nrows = BLK - chunk * 64;
  if (nrows > 64) nrows = 64;

  for (int i = t; i < KC * HID; i += 256) ((float*)outL)[i] = 0.f;
  if (t < 16) ssL[t] = 0.f;
  if (t == 0) denL = 0.f;

  const int w = t >> 6;     // wave: cols 32w..32w+31
  const int l = t & 63;
  const int m16 = l & 15;
  const int gq = l >> 4;

  f32x4 acc[4][2];
#pragma unroll
  for (int fr = 0; fr < 4; ++fr)
#pragma unroll
    for (int fc = 0; fc < 2; ++fc) acc[fr][fc] = (f32x4){0.f, 0.f, 0.f, 0.f};

  const int arow = t >> 2;
  const int acol = (t & 3) * 8;
  const int arr = (arow < nrows) ? arow : (nrows - 1);
  const ushort* Aag = aggb + (size_t)(node0 + arr) * HID + acol;
  const ushort* Axx = xb + (size_t)(node0 + arr) * HID + acol;

#pragma unroll 1
  for (int kt = 0; kt < 8; ++kt) {
    const int kb = (kt & 3) * 32;
    __syncthreads();
    {
      const ushort* srcp = (kt < 4) ? (Aag + kb) : (Axx + kb);
      *(uint4*)&As[arow][acol] = *(const uint4*)srcp;
#pragma unroll
      for (int i = 0; i < 2; ++i) {
        int idx = i * 256 + t;
        int col = idx >> 2, ch = (idx & 3) * 8;
        *(uint4*)&Bs[col][ch] = *(const uint4*)(Wt + (size_t)col * 256 + kt * 32 + ch);
      }
    }
    __syncthreads();
    bf16x8 af[4], bfr[2];
#pragma unroll
    for (int fr = 0; fr < 4; ++fr)
      af[fr] = *(const bf16x8*)&As[16 * fr + m16][8 * gq];
#pragma unroll
    for (int fc = 0; fc < 2; ++fc)
      bfr[fc] = *(const bf16x8*)&Bs[32 * w + 16 * fc + m16][8 * gq];
#pragma unroll
    for (int fr = 0; fr < 4; ++fr)
#pragma unroll
      for (int fc = 0; fc < 2; ++fc)
        acc[fr][fc] = __builtin_amdgcn_mfma_f32_16x16x32_bf16(af[fr], bfr[fc],
                                                              acc[fr][fc], 0, 0, 0);
  }

  // bias + relu -> hL  (D layout: row = 4*(l>>4)+reg, col = l&15  [m89])
  const float bc0 = brel1[32 * w + m16];
  const float bc1 = brel1[32 * w + 16 + m16];
#pragma unroll
  for (int fr = 0; fr < 4; ++fr)
#pragma unroll
    for (int fc = 0; fc < 2; ++fc)
#pragma unroll
      for (int r = 0; r < 4; ++r)
        hL[16 * fr + 4 * gq + r][32 * w + 16 * fc + m16] =
            fmaxf(acc[fr][fc][r] + (fc ? bc1 : bc0), 0.f);
  __syncthreads();

  // ---- epilogue (16-lane groups own 4 rows each) ----
  const int g4 = t >> 4;
  const int c0 = (t & 15) << 2;
  const int li = t & 15;

  float h[4][8];
#pragma unroll
  for (int r = 0; r < 4; ++r) {
    float4 v0 = *(const float4*)&hL[g4 * 4 + r][c0];
    float4 v1 = *(const float4*)&hL[g4 * 4 + r][c0 + 64];
    h[r][0] = v0.x; h[r][1] = v0.y; h[r][2] = v0.z; h[r][3] = v0.w;
    h[r][4] = v1.x; h[r][5] = v1.y; h[r][6] = v1.z; h[r][7] = v1.w;
  }

  // pooling head: p = h @ Wpool
  float wp[8][4];
#pragma unroll
  for (int j = 0; j < 8; ++j) {
    int col = c0 + (j & 3) + (j >> 2) * 64;
    float4 v = *(const float4*)(Wpool + col * 4);
    wp[j][0] = v.x; wp[j][1] = v.y; wp[j][2] = v.z; wp[j][3] = v.w;
  }
  float pp[4][4];
#pragma unroll
  for (int r = 0; r < 4; ++r)
#pragma unroll
    for (int k = 0; k < 4; ++k) pp[r][k] = 0.f;
#pragma unroll
  for (int r = 0; r < 4; ++r)
#pragma unroll
    for (int j = 0; j < 8; ++j)
#pragma unroll
      for (int k = 0; k < 4; ++k) pp[r][k] = fmaf(h[r][j], wp[j][k], pp[r][k]);
#pragma unroll
  for (int m = 1; m <= 8; m <<= 1)
#pragma unroll
    for (int r = 0; r < 4; ++r)
#pragma unroll
      for (int k = 0; k < 4; ++k) pp[r][k] += __shfl_xor(pp[r][k], m);

  float4 bp4 = *(const float4*)bpool;
  float bp[4] = {bp4.x, bp4.y, bp4.z, bp4.w};
  float sv[4][4];
#pragma unroll
  for (int r = 0; r < 4; ++r) {
    float p[4];
#pragma unroll
    for (int k = 0; k < 4; ++k) p[k] = pp[r][k] + bp[k];
    float mx = fmaxf(fmaxf(p[0], p[1]), fmaxf(p[2], p[3]));
    float e0 = expf(p[0] - mx), e1 = expf(p[1] - mx), e2 = expf(p[2] - mx), e3 = expf(p[3] - mx);
    float inv = 1.f / (e0 + e1 + e2 + e3);
    float valid = (g4 * 4 + r < nrows) ? 1.f : 0.f;
    sv[r][0] = e0 * inv * valid; sv[r][1] = e1 * inv * valid;
    sv[r][2] = e2 * inv * valid; sv[r][3] = e3 * inv * valid;
  }

  // write s
  {
    int rW = li >> 2, kW = li & 3;
    if (g4 * 4 + rW < nrows) {
      int node = node0 + g4 * 4 + rW;
      float val = 0.f;
#pragma unroll
      for (int rr = 0; rr < 4; ++rr)
#pragma unroll
        for (int kk = 0; kk < 4; ++kk)
          if (li == rr * 4 + kk) val = sv[rr][kk];
      s_out[node * 4 + kW] = val;
    }
  }

  // ss[b][k1][k2]
  {
    int k1 = li >> 2, k2 = li & 3;
    float a1[4], a2[4];
#pragma unroll
    for (int rr = 0; rr < 4; ++rr) {
      float v1 = 0.f, v2 = 0.f;
#pragma unroll
      for (int kk = 0; kk < 4; ++kk) {
        if (k1 == kk) v1 = sv[rr][kk];
        if (k2 == kk) v2 = sv[rr][kk];
      }
      a1[rr] = v1; a2[rr] = v2;
    }
    float ssv = a1[0] * a2[0] + a1[1] * a2[1] + a1[2] * a2[2] + a1[3] * a2[3];
    atomicAdd(&ssL[li], ssv);
  }

  // den[b] += deg * ||s||^2
  if (li == 0) {
    float dent = 0.f;
#pragma unroll
    for (int rr = 0; rr < 4; ++rr) {
      int rowg = g4 * 4 + rr;
      if (rowg < nrows) {
        float dg = (float)count[node0 + rowg];
        dent += dg * (sv[rr][0] * sv[rr][0] + sv[rr][1] * sv[rr][1] +
                      sv[rr][2] * sv[rr][2] + sv[rr][3] * sv[rr][3]);
      }
    }
    atomicAdd(&denL, dent);
  }

  // out[b][k][c] += s[r][k]*h[r][c]
  float po[4][8];
#pragma unroll
  for (int k = 0; k < 4; ++k)
#pragma unroll
    for (int c = 0; c < 8; ++c) po[k][c] = 0.f;
#pragma unroll
  for (int k = 0; k < 4; ++k)
#pragma unroll
    for (int rr = 0; rr < 4; ++rr)
#pragma unroll
      for (int c = 0; c < 8; ++c) po[k][c] = fmaf(sv[rr][k], h[rr][c], po[k][c]);
#pragma unroll
  for (int k = 0; k < 4; ++k)
#pragma unroll
    for (int c = 0; c < 8; ++c) {
      po[k][c] += __shfl_xor(po[k][c], 16);
      po[k][c] += __shfl_xor(po[k][c], 32);
    }
  if ((t & 63) < 16) {
#pragma unroll
    for (int k = 0; k < 4; ++k)
#pragma unroll
      for (int c = 0; c < 8; ++c)
        atomicAdd(&outL[k][c0 + (c & 3) + (c >> 2) * 64], po[k][c]);
  }

  __syncthreads();
  for (int i = t; i < KC * HID; i += 256)
    atomicAdd(&out_pool[bG * KC * HID + i], ((const float*)outL)[i]);
  if (t < 16) atomicAdd(&ss_g[bG * 16 + t], ssL[t]);
  if (t == 0) atomicAdd(&den_g[bG], denL);
}

// ---------------------------------------------------------------- K4: out_adj[b] = sum_n s[n] (x) t[n],  t[n] = sum_{e: dst=n} s[src]
__global__ __launch_bounds__(256) void k_adj2(const int* __restrict__ count,
                                              const int* __restrict__ rowptr,
                                              const int* __restrict__ csr,
                                              const float* __restrict__ s,
                                              float* __restrict__ adjraw) {
  __shared__ float accL[4][2][16];  // [wave][graph-within-block][k1*4+k2]
  const int t = threadIdx.x;
  if (t < 128) ((float*)accL)[t] = 0.f;
  __syncthreads();
  const int node = blockIdx.x * 256 + t;
  const int g0 = (blockIdx.x * 256) / BLK;
  if (node < NN) {
    const int gi = node / BLK - g0;  // 0 or 1
    const int deg = count[node];
    const int* sl = csr + rowptr[node];
    float t0 = 0.f, t1 = 0.f, t2 = 0.f, t3 = 0.f;
    for (int e = 0; e < deg; ++e) {
      float4 svv = *(const float4*)(s + (size_t)sl[e] * 4);
      t0 += svv.x; t1 += svv.y; t2 += svv.z; t3 += svv.w;
    }
    float4 sn = *(const float4*)(s + (size_t)node * 4);
    float* base = accL[t >> 6][gi];
#pragma unroll
    for (int i = 0; i < 16; ++i) {
      int idx = (i + t) & 15;  // stagger: 4-way instead of 64-way contention
      int hi = idx >> 2, lo = idx & 3;
      float a = (hi == 0) ? sn.x : (hi == 1) ? sn.y : (hi == 2) ? sn.z : sn.w;
      float b = (lo == 0) ? t0 : (lo == 1) ? t1 : (lo == 2) ? t2 : t3;
      atomicAdd(base + idx, a * b);
    }
  }
  __syncthreads();
  if (t < 32) {
    int gi = t >> 4, i = t & 15, gg = g0 + gi;
    if (gg < NB) {
      float v = accL[0][gi][i] + accL[1][gi][i] + accL[2][gi][i] + accL[3][gi][i];
      atomicAdd(&adjraw[gg * 16 + i], v);
    }
  }
}

// ---------------------------------------------------------------- K5a: per-graph tail
__global__ __launch_bounds__(128) void k_graph(
    const float* __restrict__ out_pool, const float* __restrict__ adjraw,
    const float* __restrict__ den_g, const float* __restrict__ ss_g,
    const float* __restrict__ Wrel3, const float* __restrict__ brel3,
    const float* __restrict__ Wroot3, const float* __restrict__ Wlin1,
    const float* __restrict__ blin1, const float* __restrict__ Wlin2,
    const float* __restrict__ blin2, float* __restrict__ d_out,
    float* __restrict__ scratch) {
  const int b = blockIdx.x, t = threadIdx.x;
  __shared__ float adjL[16], adjnL[16], dL[4];
  __shared__ float osL[128], msL[128], x2mL[128], x3L[128];
  if (t < 16) adjL[t] = adjraw[b * 16 + t];
  __syncthreads();
  if (t < 4) {
    float srow = 0.f;
#pragma unroll
    for (int l = 0; l < 4; ++l)
      if (l != t) srow += adjL[t * 4 + l];
    dL[t] = sqrtf(srow) + 1e-15f;
  }
  __syncthreads();
  if (t < 16) {
    int k1 = t >> 2, k2 = t & 3;
    float az = (k1 == k2) ? 0.f : adjL[t];
    float an = az / (dL[k2] * dL[k1]);
    adjnL[t] = an;
    d_out[400018 + b * 16 + t] = an;
  }
  __syncthreads();
  float o0 = out_pool[b * 512 + 0 * 128 + t];
  float o1 = out_pool[b * 512 + 1 * 128 + t];
  float o2 = out_pool[b * 512 + 2 * 128 + t];
  float o3 = out_pool[b * 512 + 3 * 128 + t];
  float m0 = adjnL[0] * o0 + adjnL[1] * o1 + adjnL[2] * o2 + adjnL[3] * o3;
  float m1 = adjnL[4] * o0 + adjnL[5] * o1 + adjnL[6] * o2 + adjnL[7] * o3;
  float m2 = adjnL[8] * o0 + adjnL[9] * o1 + adjnL[10] * o2 + adjnL[11] * o3;
  float m3 = adjnL[12] * o0 + adjnL[13] * o1 + adjnL[14] * o2 + adjnL[15] * o3;
  osL[t] = o0 + o1 + o2 + o3;
  msL[t] = m0 + m1 + m2 + m3;
  __syncthreads();
  float accc = brel3[t];
  for (int j = 0; j < 128; ++j)
    accc += 0.25f * (msL[j] * Wrel3[j * 128 + t] + osL[j] * Wroot3[j * 128 + t]);
  x2mL[t] = accc;
  __syncthreads();
  float a2 = blin1[t];
  for (int j = 0; j < 128; ++j) a2 += x2mL[j] * Wlin1[j * 128 + t];
  x3L[t] = fmaxf(a2, 0.f);
  __syncthreads();
  if (t < 2) {
    float lg = blin2[t];
    for (int j = 0; j < 128; ++j) lg += x3L[j] * Wlin2[j * 2 + t];
    scratch[b * 2 + t] = lg;
  }
  if (t == 0) {
    float tr = adjL[0] + adjL[5] + adjL[10] + adjL[15];
    scratch[16 + b] = tr / den_g[b];
    float n2 = 0.f;
    for (int i = 0; i < 16; ++i) { float v = ss_g[b * 16 + i]; n2 += v * v; }
    float nn = sqrtf(n2);
    float od = 0.f;
    for (int i = 0; i < 16; ++i) {
      float v = ss_g[b * 16 + i] / nn - (((i >> 2) == (i & 3)) ? 0.5f : 0.f);
      od += v * v;
    }
    scratch[24 + b] = sqrtf(od);
  }
}

// ---------------------------------------------------------------- K5b: losses + log_softmax
__global__ void k_final(const float* __restrict__ scratch, float* __restrict__ d_out) {
  if (threadIdx.x == 0 && blockIdx.x == 0) {
    float mc = 0.f, oo = 0.f;
    for (int b = 0; b < NB; ++b) { mc += scratch[16 + b]; oo += scratch[24 + b]; }
    d_out[16] = -(mc / (float)NB);
    d_out[17] = oo / (float)NB;
    for (int b = 0; b < NB; ++b) {
      float l0 = scratch[2 * b], l1 = scratch[2 * b + 1];
      float m = fmaxf(l0, l1);
      float lse = m + logf(expf(l0 - m) + expf(l1 - m));
      d_out[2 * b] = l0 - lse;
      d_out[2 * b + 1] = l1 - lse;
    }
  }
}

// ---------------------------------------------------------------- launch
extern "C" void kernel_launch(void* const* d_in, const int* in_sizes, int n_in,
                              void* d_out, int out_size, void* d_ws, size_t ws_size,
                              hipStream_t stream) {
  (void)in_sizes; (void)n_in; (void)out_size; (void)ws_size;
  const float* x      = (const float*)d_in[0];
  const int*   ei     = (const int*)d_in[1];
  const float* Wroot1 = (const float*)d_in[3];
  const float* Wrel1  = (const float*)d_in[4];
  const float* brel1  = (const float*)d_in[5];
  const float* Wpool  = (const float*)d_in[6];
  const float* bpool  = (const float*)d_in[7];
  const float* Wrel3  = (const float*)d_in[8];
  const float* brel3  = (const float*)d_in[9];
  const float* Wroot3 = (const float*)d_in[10];
  const float* Wlin1  = (const float*)d_in[11];
  const float* blin1  = (const float*)d_in[12];
  const float* Wlin2  = (const float*)d_in[13];
  const float* blin2  = (const float*)d_in[14];
  float* out = (float*)d_out;

  char* ws = (char*)d_ws;
  int*    count    = (int*)(ws + 0);            //   400000 B (memset)
  float*  out_pool = (float*)(ws + 400000);     //    16384 B (memset)
  float*  ss_g     = (float*)(ws + 416384);     //      512 B (memset)
  float*  adjraw   = (float*)(ws + 416896);     //      512 B (memset)
  float*  den_g    = (float*)(ws + 417408);     //       32 B (memset)
  float*  scratch  = (float*)(ws + 417440);     //      128 B (memset)
  int*    gcur     = (int*)(ws + 417568);       //       32 B (memset)
  int*    rowptr   = (int*)(ws + 417600);       //   400016 B
  int*    cursor   = (int*)(ws + 817616);       //   400016 B
  int*    blocksum = (int*)(ws + 1217632);      //     1024 B
  ushort* Wt       = (ushort*)(ws + 1218656);   //    65536 B [128][256]
  int*    csr      = (int*)(ws + 1284192);      //  6400000 B [E]
  ushort* xb       = (ushort*)(ws + 7684192);   // 25600000 B [N][128] bf16
  ushort* aggb     = (ushort*)(ws + 33284192);  // 25600000 B [N][128] bf16
  // gbuf (8 x 262144 x 4 B = 8.4 MB) aliases aggb: consumed by k_count_b /
  // k_fill_b strictly before k_agg2 writes aggb (same stream, serialized).
  uint*   gbuf     = (uint*)(ws + 33284192);

  hipMemsetAsync(ws, 0, 417600, stream);
  k_prep_x<<<12500, 256, 0, stream>>>((const float4*)x, xb);
  k_prep_w<<<128, 256, 0, stream>>>(Wrel1, Wroot1, Wt);
  k_bucket<<<(EE + 2047) / 2048, 256, 0, stream>>>(ei, gcur, gbuf);
  k_count_b<<<8 * 64, 256, 0, stream>>>(gbuf, gcur, count);
  k_scanA<<<SCANB, 256, 0, stream>>>(count, blocksum);
  k_scanB<<<1, 256, 0, stream>>>(blocksum);
  k_scanC<<<SCANB, 256, 0, stream>>>(count, blocksum, rowptr, cursor);
  k_fill_b<<<8 * 64, 256, 0, stream>>>(gbuf, gcur, cursor, csr);
  k_agg2<<<8 * ((BLK + 7) / 8), 256, 0, stream>>>(xb, count, rowptr, csr, aggb);
  k_fused<<<NB * CHUNKS, 256, 0, stream>>>(aggb, xb, Wt, brel1, Wpool, bpool, count,
                                           out + 18, out_pool, ss_g, den_g);
  k_adj2<<<(NN + 255) / 256, 256, 0, stream>>>(count, rowptr, csr, out + 18, adjraw);
  k_graph<<<NB, 128, 0, stream>>>(out_pool, adjraw, den_g, ss_g, Wrel3, brel3, Wroot3,
                                  Wlin1, blin1, Wlin2, blin2, out, scratch);
  k_final<<<1, 64, 0, stream>>>(scratch, out);
}

// Round 7
// 233.253 us; speedup vs baseline: 1.5806x; 1.4102x over previous
//
#include <hip/hip_runtime.h>

// Problem constants (fixed by the reference)
#define NN     100000      // nodes
#define EE     1600000     // edges
#define NB     8           // graphs
#define BLK    12500       // nodes per graph
#define HID    128
#define KC     4
#define CHUNKS 196         // ceil(12500/64)
#define NTILE  49          // dst-ranges of 256 nodes per graph
#define NBIN   392         // 8 graphs x 49 tiles
#define GCAPS  5120        // per-bin capacity (mean 4081, sigma ~64)

typedef __attribute__((ext_vector_type(8))) short bf16x8;
typedef __attribute__((ext_vector_type(4))) float f32x4;

__device__ __forceinline__ ushort f2bf(float f) {
  uint u = __float_as_uint(f);
  return (ushort)((u + 0x7FFFu + ((u >> 16) & 1u)) >> 16);  // RNE
}
__device__ __forceinline__ float bf2f(ushort h) {
  return __uint_as_float(((uint)h) << 16);
}

// ---------------------------------------------------------------- K0a: x -> bf16
__global__ __launch_bounds__(256) void k_prep_x(const float4* __restrict__ x4,
                                                ushort* __restrict__ xb) {
  int i = blockIdx.x * 256 + threadIdx.x;  // 3.2M float4s exactly
  float4 v = x4[i];
  ushort4 r;
  r.x = f2bf(v.x); r.y = f2bf(v.y); r.z = f2bf(v.z); r.w = f2bf(v.w);
  *(ushort4*)(xb + (size_t)i * 4) = r;
}

// ---------------------------------------------------------------- K0b: Wt[col][k], k<128 = Wrel1, k>=128 = Wroot1
__global__ __launch_bounds__(256) void k_prep_w(const float* __restrict__ Wrel1,
                                                const float* __restrict__ Wroot1,
                                                ushort* __restrict__ Wt) {
  int col = blockIdx.x, k = threadIdx.x;
  float v = (k < 128) ? Wrel1[k * 128 + col] : Wroot1[(k - 128) * 128 + col];
  Wt[col * 256 + k] = f2bf(v);
}

// ---------------------------------------------------------------- K1a: edges -> 392 (graph, dst-range) sub-buckets
// gfx950 L2 does NOT write-allocate on store miss (R3/R6: huge WRITE_SIZE,
// tiny FETCH) -> isolated scattered stores cost a partial line each. So:
// stage 8192 edges in LDS, sort by bin, flush each bin's chunk (~84 B)
// contiguously -> ~1.5x line amplification instead of ~10x.
__global__ __launch_bounds__(256) void k_bucket2(const int* __restrict__ ei,
                                                 int* __restrict__ sbcnt,
                                                 uint* __restrict__ gbuf) {
  __shared__ uint stage[8192];
  __shared__ int cnt[NBIN], start[NBIN + 1], rbase[NBIN];
  __shared__ int gtot[8], gb[8];
  const int t = threadIdx.x;
  for (int b = t; b < NBIN; b += 256) cnt[b] = 0;
  __syncthreads();
  const int e0 = blockIdx.x * 8192;
  uint pk[32]; int br[32];
#pragma unroll
  for (int i = 0; i < 32; ++i) {
    int e = e0 + i * 256 + t;
    bool val = (e < EE);
    int src = 0, dst = 0;
    if (val) {
      src = __builtin_nontemporal_load(ei + e);
      dst = __builtin_nontemporal_load(ei + EE + e);
    }
    int g = dst / BLK;
    int dl = dst - g * BLK;
    int sl = src - g * BLK;
    int bin = g * NTILE + (dl >> 8);
    pk[i] = ((uint)sl << 16) | (uint)dl;
    br[i] = val ? ((bin << 14) | atomicAdd(&cnt[bin], 1)) : -1;
  }
  __syncthreads();
  // exclusive scan of cnt[392] -> start[] (8 threads x 49 serial + combine)
  if (t < 8) {
    int s = 0;
    for (int k = 0; k < NTILE; ++k) s += cnt[t * NTILE + k];
    gtot[t] = s;
  }
  __syncthreads();
  if (t == 0) {
    int s = 0;
    for (int g = 0; g < 8; ++g) { gb[g] = s; s += gtot[g]; }
    start[NBIN] = s;
  }
  __syncthreads();
  if (t < 8) {
    int run = gb[t];
    for (int k = 0; k < NTILE; ++k) { start[t * NTILE + k] = run; run += cnt[t * NTILE + k]; }
  }
  __syncthreads();
  for (int b = t; b < NBIN; b += 256) rbase[b] = atomicAdd(&sbcnt[b], cnt[b]);
#pragma unroll
  for (int i = 0; i < 32; ++i) {
    if (br[i] >= 0) {
      int bin = br[i] >> 14, rank = br[i] & 16383;
      stage[start[bin] + rank] = pk[i];
    }
  }
  __syncthreads();
  const int total = start[NBIN];
  for (int j = t; j < total; j += 256) {
    int lo = 0, hi = NBIN - 1;  // largest bin with start[bin] <= j
    while (lo < hi) { int mid = (lo + hi + 1) >> 1; if (j >= start[mid]) lo = mid; else hi = mid - 1; }
    gbuf[(size_t)lo * GCAPS + rbase[lo] + (j - start[lo])] = stage[j];
  }
}

// ---------------------------------------------------------------- K1b: exclusive scan of bin sizes
__global__ __launch_bounds__(512) void k_scan392(const int* __restrict__ sbcnt,
                                                 int* __restrict__ sbbase) {
  __shared__ int sd[512];
  const int t = threadIdx.x;
  int v = (t < NBIN) ? sbcnt[t] : 0;
  sd[t] = v;
  __syncthreads();
  for (int s = 1; s < 512; s <<= 1) {
    int x = (t >= s) ? sd[t - s] : 0;
    __syncthreads();
    sd[t] += x;
    __syncthreads();
  }
  if (t < NBIN) sbbase[t] = sd[t] - v;
}

// ---------------------------------------------------------------- K1c: per-bin LDS counting sort -> dense CSR segment + rowptr + count
__global__ __launch_bounds__(256) void k_csr_tile(const uint* __restrict__ gbuf,
                                                  const int* __restrict__ sbcnt,
                                                  const int* __restrict__ sbbase,
                                                  int* __restrict__ rowptr,
                                                  int* __restrict__ count,
                                                  int* __restrict__ csr) {
  const int g = blockIdx.x & 7;     // XCD-local per graph
  const int tile = blockIdx.x >> 3; // 0..48
  const int bin = g * NTILE + tile;
  const int m = sbcnt[bin];
  const int base = sbbase[bin];
  const int n0t = tile * 256;
  const int nt = min(256, BLK - n0t);
  __shared__ uint ent[GCAPS];
  __shared__ ushort srt[GCAPS];
  __shared__ int cnt[256], scn[256], cur[256];
  const int t = threadIdx.x;
  cnt[t] = 0;
  __syncthreads();
  const uint* buf = gbuf + (size_t)bin * GCAPS;
  for (int i = t; i < m; i += 256) {
    uint pk = buf[i];
    ent[i] = pk;
    atomicAdd(&cnt[(int)(pk & 0xFFFFu) - n0t], 1);
  }
  __syncthreads();
  int v = cnt[t];
  scn[t] = v;
  __syncthreads();
  for (int s = 1; s < 256; s <<= 1) {
    int x = (t >= s) ? scn[t - s] : 0;
    __syncthreads();
    scn[t] += x;
    __syncthreads();
  }
  int excl = scn[t] - v;
  cur[t] = excl;
  if (t < nt) {
    rowptr[g * BLK + n0t + t] = base + excl;
    count[g * BLK + n0t + t] = v;
  }
  __syncthreads();
  for (int i = t; i < m; i += 256) {
    uint pk = ent[i];
    int p = atomicAdd(&cur[(int)(pk & 0xFFFFu) - n0t], 1);
    srt[p] = (ushort)(pk >> 16);
  }
  __syncthreads();
  const int nb = g * BLK;
  for (int i = t; i < m; i += 256)
    csr[base + i] = nb + (int)srt[i];  // dense coalesced
}

// ---------------------------------------------------------------- K2: agg[n] = sum_{e: dst=n} x[src]  (bf16, fp32 accum)
__global__ __launch_bounds__(256) void k_agg2(const ushort* __restrict__ xb,
                                              const int* __restrict__ count,
                                              const int* __restrict__ rowptr,
                                              const int* __restrict__ csr,
                                              ushort* __restrict__ aggb) {
  const int xg = blockIdx.x & 7;
  const int j = blockIdx.x >> 3;
  const int half = threadIdx.x >> 5;  // 8 half-waves = 8 nodes per block
  const int lane = threadIdx.x & 31;
  const int ln = j * 8 + half;
  if (ln >= BLK) return;
  const int node = xg * BLK + ln;
  const int deg = count[node];
  const int* sl = csr + rowptr[node];
  int idx0 = (lane < deg) ? sl[lane] : 0;
  int idx1 = (32 + lane < deg) ? sl[32 + lane] : 0;
  float a0 = 0.f, a1 = 0.f, a2 = 0.f, a3 = 0.f;
  for (int e = 0; e < deg; ++e) {
    int srcn = (e < 32) ? __shfl(idx0, e, 32)
                        : ((e < 64) ? __shfl(idx1, e - 32, 32) : sl[e]);
    ushort4 v = *(const ushort4*)(xb + (size_t)srcn * HID + lane * 4);
    a0 += bf2f(v.x); a1 += bf2f(v.y); a2 += bf2f(v.z); a3 += bf2f(v.w);
  }
  ushort4 r;
  r.x = f2bf(a0); r.y = f2bf(a1); r.z = f2bf(a2); r.w = f2bf(a3);
  *(ushort4*)(aggb + (size_t)node * HID + lane * 4) = r;
}

// ---------------------------------------------------------------- K3: MFMA GEMM + softmax + pooled reductions
__global__ __launch_bounds__(256) void k_fused(
    const ushort* __restrict__ aggb, const ushort* __restrict__ xb,
    const ushort* __restrict__ Wt, const float* __restrict__ brel1,
    const float* __restrict__ Wpool, const float* __restrict__ bpool,
    const int* __restrict__ count, float* __restrict__ s_out,
    float* __restrict__ out_pool, float* __restrict__ ss_g,
    float* __restrict__ den_g) {
  __shared__ ushort As[64][40];    // 64 rows x 32 k (pad->40)
  __shared__ ushort Bs[128][40];   // 128 cols x 32 k
  __shared__ float hL[64][132];    // h tile (pad 128->132)
  __shared__ float outL[KC][HID];
  __shared__ float ssL[16];
  __shared__ float denL;

  const int t = threadIdx.x;
  const int bG = blockIdx.x / CHUNKS;
  const int chunk = blockIdx.x % CHUNKS;
  const int node0 = bG * BLK + chunk * 64;
  int nrows = BLK - chunk * 64;
  if (nrows > 64) nrows = 64;

  for (int i = t; i < KC * HID; i += 256) ((float*)outL)[i] = 0.f;
  if (t < 16) ssL[t] = 0.f;
  if (t == 0) denL = 0.f;

  const int w = t >> 6;     // wave: cols 32w..32w+31
  const int l = t & 63;
  const int m16 = l & 15;
  const int gq = l >> 4;

  f32x4 acc[4][2];
#pragma unroll
  for (int fr = 0; fr < 4; ++fr)
#pragma unroll
    for (int fc = 0; fc < 2; ++fc) acc[fr][fc] = (f32x4){0.f, 0.f, 0.f, 0.f};

  const int arow = t >> 2;
  const int acol = (t & 3) * 8;
  const int arr = (arow < nrows) ? arow : (nrows - 1);
  const ushort* Aag = aggb + (size_t)(node0 + arr) * HID + acol;
  const ushort* Axx = xb + (size_t)(node0 + arr) * HID + acol;

#pragma unroll 1
  for (int kt = 0; kt < 8; ++kt) {
    const int kb = (kt & 3) * 32;
    __syncthreads();
    {
      const ushort* srcp = (kt < 4) ? (Aag + kb) : (Axx + kb);
      *(uint4*)&As[arow][acol] = *(const uint4*)srcp;
#pragma unroll
      for (int i = 0; i < 2; ++i) {
        int idx = i * 256 + t;
        int col = idx >> 2, ch = (idx & 3) * 8;
        *(uint4*)&Bs[col][ch] = *(const uint4*)(Wt + (size_t)col * 256 + kt * 32 + ch);
      }
    }
    __syncthreads();
    bf16x8 af[4], bfr[2];
#pragma unroll
    for (int fr = 0; fr < 4; ++fr)
      af[fr] = *(const bf16x8*)&As[16 * fr + m16][8 * gq];
#pragma unroll
    for (int fc = 0; fc < 2; ++fc)
      bfr[fc] = *(const bf16x8*)&Bs[32 * w + 16 * fc + m16][8 * gq];
#pragma unroll
    for (int fr = 0; fr < 4; ++fr)
#pragma unroll
      for (int fc = 0; fc < 2; ++fc)
        acc[fr][fc] = __builtin_amdgcn_mfma_f32_16x16x32_bf16(af[fr], bfr[fc],
                                                              acc[fr][fc], 0, 0, 0);
  }

  // bias + relu -> hL  (D layout: row = 4*(l>>4)+reg, col = l&15  [m89])
  const float bc0 = brel1[32 * w + m16];
  const float bc1 = brel1[32 * w + 16 + m16];
#pragma unroll
  for (int fr = 0; fr < 4; ++fr)
#pragma unroll
    for (int fc = 0; fc < 2; ++fc)
#pragma unroll
      for (int r = 0; r < 4; ++r)
        hL[16 * fr + 4 * gq + r][32 * w + 16 * fc + m16] =
            fmaxf(acc[fr][fc][r] + (fc ? bc1 : bc0), 0.f);
  __syncthreads();

  // ---- epilogue (16-lane groups own 4 rows each) ----
  const int g4 = t >> 4;
  const int c0 = (t & 15) << 2;
  const int li = t & 15;

  float h[4][8];
#pragma unroll
  for (int r = 0; r < 4; ++r) {
    float4 v0 = *(const float4*)&hL[g4 * 4 + r][c0];
    float4 v1 = *(const float4*)&hL[g4 * 4 + r][c0 + 64];
    h[r][0] = v0.x; h[r][1] = v0.y; h[r][2] = v0.z; h[r][3] = v0.w;
    h[r][4] = v1.x; h[r][5] = v1.y; h[r][6] = v1.z; h[r][7] = v1.w;
  }

  // pooling head: p = h @ Wpool
  float wp[8][4];
#pragma unroll
  for (int j = 0; j < 8; ++j) {
    int col = c0 + (j & 3) + (j >> 2) * 64;
    float4 v = *(const float4*)(Wpool + col * 4);
    wp[j][0] = v.x; wp[j][1] = v.y; wp[j][2] = v.z; wp[j][3] = v.w;
  }
  float pp[4][4];
#pragma unroll
  for (int r = 0; r < 4; ++r)
#pragma unroll
    for (int k = 0; k < 4; ++k) pp[r][k] = 0.f;
#pragma unroll
  for (int r = 0; r < 4; ++r)
#pragma unroll
    for (int j = 0; j < 8; ++j)
#pragma unroll
      for (int k = 0; k < 4; ++k) pp[r][k] = fmaf(h[r][j], wp[j][k], pp[r][k]);
#pragma unroll
  for (int m = 1; m <= 8; m <<= 1)
#pragma unroll
    for (int r = 0; r < 4; ++r)
#pragma unroll
      for (int k = 0; k < 4; ++k) pp[r][k] += __shfl_xor(pp[r][k], m);

  float4 bp4 = *(const float4*)bpool;
  float bp[4] = {bp4.x, bp4.y, bp4.z, bp4.w};
  float sv[4][4];
#pragma unroll
  for (int r = 0; r < 4; ++r) {
    float p[4];
#pragma unroll
    for (int k = 0; k < 4; ++k) p[k] = pp[r][k] + bp[k];
    float mx = fmaxf(fmaxf(p[0], p[1]), fmaxf(p[2], p[3]));
    float e0 = expf(p[0] - mx), e1 = expf(p[1] - mx), e2 = expf(p[2] - mx), e3 = expf(p[3] - mx);
    float inv = 1.f / (e0 + e1 + e2 + e3);
    float valid = (g4 * 4 + r < nrows) ? 1.f : 0.f;
    sv[r][0] = e0 * inv * valid; sv[r][1] = e1 * inv * valid;
    sv[r][2] = e2 * inv * valid; sv[r][3] = e3 * inv * valid;
  }

  // write s
  {
    int rW = li >> 2, kW = li & 3;
    if (g4 * 4 + rW < nrows) {
      int node = node0 + g4 * 4 + rW;
      float val = 0.f;
#pragma unroll
      for (int rr = 0; rr < 4; ++rr)
#pragma unroll
        for (int kk = 0; kk < 4; ++kk)
          if (li == rr * 4 + kk) val = sv[rr][kk];
      s_out[node * 4 + kW] = val;
    }
  }

  // ss[b][k1][k2]
  {
    int k1 = li >> 2, k2 = li & 3;
    float a1[4], a2[4];
#pragma unroll
    for (int rr = 0; rr < 4; ++rr) {
      float v1 = 0.f, v2 = 0.f;
#pragma unroll
      for (int kk = 0; kk < 4; ++kk) {
        if (k1 == kk) v1 = sv[rr][kk];
        if (k2 == kk) v2 = sv[rr][kk];
      }
      a1[rr] = v1; a2[rr] = v2;
    }
    float ssv = a1[0] * a2[0] + a1[1] * a2[1] + a1[2] * a2[2] + a1[3] * a2[3];
    atomicAdd(&ssL[li], ssv);
  }

  // den[b] += deg * ||s||^2
  if (li == 0) {
    float dent = 0.f;
#pragma unroll
    for (int rr = 0; rr < 4; ++rr) {
      int rowg = g4 * 4 + rr;
      if (rowg < nrows) {
        float dg = (float)count[node0 + rowg];
        dent += dg * (sv[rr][0] * sv[rr][0] + sv[rr][1] * sv[rr][1] +
                      sv[rr][2] * sv[rr][2] + sv[rr][3] * sv[rr][3]);
      }
    }
    atomicAdd(&denL, dent);
  }

  // out[b][k][c] += s[r][k]*h[r][c]
  float po[4][8];
#pragma unroll
  for (int k = 0; k < 4; ++k)
#pragma unroll
    for (int c = 0; c < 8; ++c) po[k][c] = 0.f;
#pragma unroll
  for (int k = 0; k < 4; ++k)
#pragma unroll
    for (int rr = 0; rr < 4; ++rr)
#pragma unroll
      for (int c = 0; c < 8; ++c) po[k][c] = fmaf(sv[rr][k], h[rr][c], po[k][c]);
#pragma unroll
  for (int k = 0; k < 4; ++k)
#pragma unroll
    for (int c = 0; c < 8; ++c) {
      po[k][c] += __shfl_xor(po[k][c], 16);
      po[k][c] += __shfl_xor(po[k][c], 32);
    }
  if ((t & 63) < 16) {
#pragma unroll
    for (int k = 0; k < 4; ++k)
#pragma unroll
      for (int c = 0; c < 8; ++c)
        atomicAdd(&outL[k][c0 + (c & 3) + (c >> 2) * 64], po[k][c]);
  }

  __syncthreads();
  for (int i = t; i < KC * HID; i += 256)
    atomicAdd(&out_pool[bG * KC * HID + i], ((const float*)outL)[i]);
  if (t < 16) atomicAdd(&ss_g[bG * 16 + t], ssL[t]);
  if (t == 0) atomicAdd(&den_g[bG], denL);
}

// ---------------------------------------------------------------- K4: out_adj[b] = sum_n s[n] (x) t[n],  t[n] = sum_{e: dst=n} s[src]
__global__ __launch_bounds__(256) void k_adj2(const int* __restrict__ count,
                                              const int* __restrict__ rowptr,
                                              const int* __restrict__ csr,
                                              const float* __restrict__ s,
                                              float* __restrict__ adjraw) {
  __shared__ float accL[4][2][16];  // [wave][graph-within-block][k1*4+k2]
  const int t = threadIdx.x;
  if (t < 128) ((float*)accL)[t] = 0.f;
  __syncthreads();
  const int node = blockIdx.x * 256 + t;
  const int g0 = (blockIdx.x * 256) / BLK;
  if (node < NN) {
    const int gi = node / BLK - g0;  // 0 or 1
    const int deg = count[node];
    const int* sl = csr + rowptr[node];
    float t0 = 0.f, t1 = 0.f, t2 = 0.f, t3 = 0.f;
    for (int e = 0; e < deg; ++e) {
      float4 svv = *(const float4*)(s + (size_t)sl[e] * 4);
      t0 += svv.x; t1 += svv.y; t2 += svv.z; t3 += svv.w;
    }
    float4 sn = *(const float4*)(s + (size_t)node * 4);
    float* base = accL[t >> 6][gi];
#pragma unroll
    for (int i = 0; i < 16; ++i) {
      int idx = (i + t) & 15;  // stagger: 4-way instead of 64-way contention
      int hi = idx >> 2, lo = idx & 3;
      float a = (hi == 0) ? sn.x : (hi == 1) ? sn.y : (hi == 2) ? sn.z : sn.w;
      float b = (lo == 0) ? t0 : (lo == 1) ? t1 : (lo == 2) ? t2 : t3;
      atomicAdd(base + idx, a * b);
    }
  }
  __syncthreads();
  if (t < 32) {
    int gi = t >> 4, i = t & 15, gg = g0 + gi;
    if (gg < NB) {
      float v = accL[0][gi][i] + accL[1][gi][i] + accL[2][gi][i] + accL[3][gi][i];
      atomicAdd(&adjraw[gg * 16 + i], v);
    }
  }
}

// ---------------------------------------------------------------- K5a: per-graph tail
__global__ __launch_bounds__(128) void k_graph(
    const float* __restrict__ out_pool, const float* __restrict__ adjraw,
    const float* __restrict__ den_g, const float* __restrict__ ss_g,
    const float* __restrict__ Wrel3, const float* __restrict__ brel3,
    const float* __restrict__ Wroot3, const float* __restrict__ Wlin1,
    const float* __restrict__ blin1, const float* __restrict__ Wlin2,
    const float* __restrict__ blin2, float* __restrict__ d_out,
    float* __restrict__ scratch) {
  const int b = blockIdx.x, t = threadIdx.x;
  __shared__ float adjL[16], adjnL[16], dL[4];
  __shared__ float osL[128], msL[128], x2mL[128], x3L[128];
  if (t < 16) adjL[t] = adjraw[b * 16 + t];
  __syncthreads();
  if (t < 4) {
    float srow = 0.f;
#pragma unroll
    for (int l = 0; l < 4; ++l)
      if (l != t) srow += adjL[t * 4 + l];
    dL[t] = sqrtf(srow) + 1e-15f;
  }
  __syncthreads();
  if (t < 16) {
    int k1 = t >> 2, k2 = t & 3;
    float az = (k1 == k2) ? 0.f : adjL[t];
    float an = az / (dL[k2] * dL[k1]);
    adjnL[t] = an;
    d_out[400018 + b * 16 + t] = an;
  }
  __syncthreads();
  float o0 = out_pool[b * 512 + 0 * 128 + t];
  float o1 = out_pool[b * 512 + 1 * 128 + t];
  float o2 = out_pool[b * 512 + 2 * 128 + t];
  float o3 = out_pool[b * 512 + 3 * 128 + t];
  float m0 = adjnL[0] * o0 + adjnL[1] * o1 + adjnL[2] * o2 + adjnL[3] * o3;
  float m1 = adjnL[4] * o0 + adjnL[5] * o1 + adjnL[6] * o2 + adjnL[7] * o3;
  float m2 = adjnL[8] * o0 + adjnL[9] * o1 + adjnL[10] * o2 + adjnL[11] * o3;
  float m3 = adjnL[12] * o0 + adjnL[13] * o1 + adjnL[14] * o2 + adjnL[15] * o3;
  osL[t] = o0 + o1 + o2 + o3;
  msL[t] = m0 + m1 + m2 + m3;
  __syncthreads();
  float accc = brel3[t];
  for (int j = 0; j < 128; ++j)
    accc += 0.25f * (msL[j] * Wrel3[j * 128 + t] + osL[j] * Wroot3[j * 128 + t]);
  x2mL[t] = accc;
  __syncthreads();
  float a2 = blin1[t];
  for (int j = 0; j < 128; ++j) a2 += x2mL[j] * Wlin1[j * 128 + t];
  x3L[t] = fmaxf(a2, 0.f);
  __syncthreads();
  if (t < 2) {
    float lg = blin2[t];
    for (int j = 0; j < 128; ++j) lg += x3L[j] * Wlin2[j * 2 + t];
    scratch[b * 2 + t] = lg;
  }
  if (t == 0) {
    float tr = adjL[0] + adjL[5] + adjL[10] + adjL[15];
    scratch[16 + b] = tr / den_g[b];
    float n2 = 0.f;
    for (int i = 0; i < 16; ++i) { float v = ss_g[b * 16 + i]; n2 += v * v; }
    float nn = sqrtf(n2);
    float od = 0.f;
    for (int i = 0; i < 16; ++i) {
      float v = ss_g[b * 16 + i] / nn - (((i >> 2) == (i & 3)) ? 0.5f : 0.f);
      od += v * v;
    }
    scratch[24 + b] = sqrtf(od);
  }
}

// ---------------------------------------------------------------- K5b: losses + log_softmax
__global__ void k_final(const float* __restrict__ scratch, float* __restrict__ d_out) {
  if (threadIdx.x == 0 && blockIdx.x == 0) {
    float mc = 0.f, oo = 0.f;
    for (int b = 0; b < NB; ++b) { mc += scratch[16 + b]; oo += scratch[24 + b]; }
    d_out[16] = -(mc / (float)NB);
    d_out[17] = oo / (float)NB;
    for (int b = 0; b < NB; ++b) {
      float l0 = scratch[2 * b], l1 = scratch[2 * b + 1];
      float m = fmaxf(l0, l1);
      float lse = m + logf(expf(l0 - m) + expf(l1 - m));
      d_out[2 * b] = l0 - lse;
      d_out[2 * b + 1] = l1 - lse;
    }
  }
}

// ---------------------------------------------------------------- launch
extern "C" void kernel_launch(void* const* d_in, const int* in_sizes, int n_in,
                              void* d_out, int out_size, void* d_ws, size_t ws_size,
                              hipStream_t stream) {
  (void)in_sizes; (void)n_in; (void)out_size; (void)ws_size;
  const float* x      = (const float*)d_in[0];
  const int*   ei     = (const int*)d_in[1];
  const float* Wroot1 = (const float*)d_in[3];
  const float* Wrel1  = (const float*)d_in[4];
  const float* brel1  = (const float*)d_in[5];
  const float* Wpool  = (const float*)d_in[6];
  const float* bpool  = (const float*)d_in[7];
  const float* Wrel3  = (const float*)d_in[8];
  const float* brel3  = (const float*)d_in[9];
  const float* Wroot3 = (const float*)d_in[10];
  const float* Wlin1  = (const float*)d_in[11];
  const float* blin1  = (const float*)d_in[12];
  const float* Wlin2  = (const float*)d_in[13];
  const float* blin2  = (const float*)d_in[14];
  float* out = (float*)d_out;

  char* ws = (char*)d_ws;
  float*  out_pool = (float*)(ws + 0);          //  16384 B (memset)
  float*  ss_g     = (float*)(ws + 16384);      //    512 B (memset)
  float*  adjraw   = (float*)(ws + 16896);      //    512 B (memset)
  float*  den_g    = (float*)(ws + 17408);      //     32 B (memset)
  float*  scratch  = (float*)(ws + 17440);      //    128 B (memset)
  int*    sbcnt    = (int*)(ws + 17568);        //   1568 B (memset)
  int*    sbbase   = (int*)(ws + 19136);        //   1600 B
  int*    count    = (int*)(ws + 20736);        // 400000 B
  int*    rowptr   = (int*)(ws + 420736);       // 400016 B
  ushort* Wt       = (ushort*)(ws + 820752);    //  65536 B [128][256]
  int*    csr      = (int*)(ws + 886288);       // 6400000 B [E]
  ushort* xb       = (ushort*)(ws + 7286288);   // 25600000 B [N][128] bf16
  ushort* aggb     = (ushort*)(ws + 32886288);  // 25600000 B [N][128] bf16
  // gbuf (392 x 5120 x 4 B = 8.03 MB) aliases aggb: consumed by k_csr_tile
  // strictly before k_agg2 writes aggb (same stream, serialized).
  uint*   gbuf     = (uint*)(ws + 32886288);

  hipMemsetAsync(ws, 0, 19136, stream);
  k_prep_x<<<12500, 256, 0, stream>>>((const float4*)x, xb);
  k_prep_w<<<128, 256, 0, stream>>>(Wrel1, Wroot1, Wt);
  k_bucket2<<<196, 256, 0, stream>>>(ei, sbcnt, gbuf);
  k_scan392<<<1, 512, 0, stream>>>(sbcnt, sbbase);
  k_csr_tile<<<NBIN, 256, 0, stream>>>(gbuf, sbcnt, sbbase, rowptr, count, csr);
  k_agg2<<<8 * ((BLK + 7) / 8), 256, 0, stream>>>(xb, count, rowptr, csr, aggb);
  k_fused<<<NB * CHUNKS, 256, 0, stream>>>(aggb, xb, Wt, brel1, Wpool, bpool, count,
                                           out + 18, out_pool, ss_g, den_g);
  k_adj2<<<(NN + 255) / 256, 256, 0, stream>>>(count, rowptr, csr, out + 18, adjraw);
  k_graph<<<NB, 128, 0, stream>>>(out_pool, adjraw, den_g, ss_g, Wrel3, brel3, Wroot3,
                                  Wlin1, blin1, Wlin2, blin2, out, scratch);
  k_final<<<1, 64, 0, stream>>>(scratch, out);
}

// Round 8
// 228.949 us; speedup vs baseline: 1.6103x; 1.0188x over previous
//
#include <hip/hip_runtime.h>

// Problem constants (fixed by the reference)
#define NN     100000      // nodes
#define EE     1600000     // edges
#define NB     8           // graphs
#define BLK    12500       // nodes per graph
#define HID    128
#define KC     4
#define CHUNKS 196         // ceil(12500/64)
#define NTILE  49          // dst-ranges of 256 nodes per graph
#define NBIN   392         // 8 graphs x 49 tiles
#define GCAPS  5120        // per-bin capacity (mean 4081, sigma ~64)

typedef __attribute__((ext_vector_type(8))) short bf16x8;
typedef __attribute__((ext_vector_type(4))) float f32x4;

__device__ __forceinline__ ushort f2bf(float f) {
  uint u = __float_as_uint(f);
  return (ushort)((u + 0x7FFFu + ((u >> 16) & 1u)) >> 16);  // RNE
}
__device__ __forceinline__ float bf2f(ushort h) {
  return __uint_as_float(((uint)h) << 16);
}

// ---------------------------------------------------------------- K0a: x -> bf16
__global__ __launch_bounds__(256) void k_prep_x(const float4* __restrict__ x4,
                                                ushort* __restrict__ xb) {
  int i = blockIdx.x * 256 + threadIdx.x;  // 3.2M float4s exactly
  float4 v = x4[i];
  ushort4 r;
  r.x = f2bf(v.x); r.y = f2bf(v.y); r.z = f2bf(v.z); r.w = f2bf(v.w);
  *(ushort4*)(xb + (size_t)i * 4) = r;
}

// ---------------------------------------------------------------- K0b: Wt[col][k], k<128 = Wrel1, k>=128 = Wroot1
__global__ __launch_bounds__(256) void k_prep_w(const float* __restrict__ Wrel1,
                                                const float* __restrict__ Wroot1,
                                                ushort* __restrict__ Wt) {
  int col = blockIdx.x, k = threadIdx.x;
  float v = (k < 128) ? Wrel1[k * 128 + col] : Wroot1[(k - 128) * 128 + col];
  Wt[col * 256 + k] = f2bf(v);
}

// ---------------------------------------------------------------- K1a: edges -> 392 (graph, dst-range) sub-buckets
// gfx950 L2 does NOT write-allocate on store miss (R3/R6) -> isolated
// scattered stores cost a partial line each. Stage 8192 edges in LDS, sort
// by bin, flush per-bin contiguous runs.
__global__ __launch_bounds__(256) void k_bucket2(const int* __restrict__ ei,
                                                 int* __restrict__ sbcnt,
                                                 uint* __restrict__ gbuf) {
  __shared__ uint stage[8192];
  __shared__ int cnt[NBIN], start[NBIN + 1], rbase[NBIN];
  __shared__ int gtot[8], gb[8];
  const int t = threadIdx.x;
  for (int b = t; b < NBIN; b += 256) cnt[b] = 0;
  __syncthreads();
  const int e0 = blockIdx.x * 8192;
  uint pk[32]; int br[32];
#pragma unroll
  for (int i = 0; i < 32; ++i) {
    int e = e0 + i * 256 + t;
    bool val = (e < EE);
    int src = 0, dst = 0;
    if (val) {
      src = __builtin_nontemporal_load(ei + e);
      dst = __builtin_nontemporal_load(ei + EE + e);
    }
    int g = dst / BLK;
    int dl = dst - g * BLK;
    int sl = src - g * BLK;
    int bin = g * NTILE + (dl >> 8);
    pk[i] = ((uint)sl << 16) | (uint)dl;
    br[i] = val ? ((bin << 14) | atomicAdd(&cnt[bin], 1)) : -1;
  }
  __syncthreads();
  if (t < 8) {
    int s = 0;
    for (int k = 0; k < NTILE; ++k) s += cnt[t * NTILE + k];
    gtot[t] = s;
  }
  __syncthreads();
  if (t == 0) {
    int s = 0;
    for (int g = 0; g < 8; ++g) { gb[g] = s; s += gtot[g]; }
    start[NBIN] = s;
  }
  __syncthreads();
  if (t < 8) {
    int run = gb[t];
    for (int k = 0; k < NTILE; ++k) { start[t * NTILE + k] = run; run += cnt[t * NTILE + k]; }
  }
  __syncthreads();
  for (int b = t; b < NBIN; b += 256) rbase[b] = atomicAdd(&sbcnt[b], cnt[b]);
#pragma unroll
  for (int i = 0; i < 32; ++i) {
    if (br[i] >= 0) {
      int bin = br[i] >> 14, rank = br[i] & 16383;
      stage[start[bin] + rank] = pk[i];
    }
  }
  __syncthreads();
  const int total = start[NBIN];
  for (int j = t; j < total; j += 256) {
    int lo = 0, hi = NBIN - 1;  // largest bin with start[bin] <= j
    while (lo < hi) { int mid = (lo + hi + 1) >> 1; if (j >= start[mid]) lo = mid; else hi = mid - 1; }
    gbuf[(size_t)lo * GCAPS + rbase[lo] + (j - start[lo])] = stage[j];
  }
}

// ---------------------------------------------------------------- K1b: exclusive scan of bin sizes
__global__ __launch_bounds__(512) void k_scan392(const int* __restrict__ sbcnt,
                                                 int* __restrict__ sbbase) {
  __shared__ int sd[512];
  const int t = threadIdx.x;
  int v = (t < NBIN) ? sbcnt[t] : 0;
  sd[t] = v;
  __syncthreads();
  for (int s = 1; s < 512; s <<= 1) {
    int x = (t >= s) ? sd[t - s] : 0;
    __syncthreads();
    sd[t] += x;
    __syncthreads();
  }
  if (t < NBIN) sbbase[t] = sd[t] - v;
}

// ---------------------------------------------------------------- K1c: per-bin LDS counting sort -> dense CSR segment + rowptr + count
__global__ __launch_bounds__(256) void k_csr_tile(const uint* __restrict__ gbuf,
                                                  const int* __restrict__ sbcnt,
                                                  const int* __restrict__ sbbase,
                                                  int* __restrict__ rowptr,
                                                  int* __restrict__ count,
                                                  int* __restrict__ csr) {
  const int g = blockIdx.x & 7;     // XCD-local per graph
  const int tile = blockIdx.x >> 3; // 0..48
  const int bin = g * NTILE + tile;
  const int m = sbcnt[bin];
  const int base = sbbase[bin];
  const int n0t = tile * 256;
  const int nt = min(256, BLK - n0t);
  __shared__ uint ent[GCAPS];
  __shared__ ushort srt[GCAPS];
  __shared__ int cnt[256], scn[256], cur[256];
  const int t = threadIdx.x;
  cnt[t] = 0;
  __syncthreads();
  const uint* buf = gbuf + (size_t)bin * GCAPS;
  for (int i = t; i < m; i += 256) {
    uint pk = buf[i];
    ent[i] = pk;
    atomicAdd(&cnt[(int)(pk & 0xFFFFu) - n0t], 1);
  }
  __syncthreads();
  int v = cnt[t];
  scn[t] = v;
  __syncthreads();
  for (int s = 1; s < 256; s <<= 1) {
    int x = (t >= s) ? scn[t - s] : 0;
    __syncthreads();
    scn[t] += x;
    __syncthreads();
  }
  int excl = scn[t] - v;
  cur[t] = excl;
  if (t < nt) {
    rowptr[g * BLK + n0t + t] = base + excl;
    count[g * BLK + n0t + t] = v;
  }
  __syncthreads();
  for (int i = t; i < m; i += 256) {
    uint pk = ent[i];
    int p = atomicAdd(&cur[(int)(pk & 0xFFFFu) - n0t], 1);
    srt[p] = (ushort)(pk >> 16);
  }
  __syncthreads();
  const int nb = g * BLK;
  for (int i = t; i < m; i += 256)
    csr[base + i] = nb + (int)srt[i];  // dense coalesced
}

// ---------------------------------------------------------------- K2: agg[n] = sum_{e: dst=n} x[src]  (bf16, fp32 accum)
__global__ __launch_bounds__(256) void k_agg2(const ushort* __restrict__ xb,
                                              const int* __restrict__ count,
                                              const int* __restrict__ rowptr,
                                              const int* __restrict__ csr,
                                              ushort* __restrict__ aggb) {
  const int xg = blockIdx.x & 7;
  const int j = blockIdx.x >> 3;
  const int half = threadIdx.x >> 5;  // 8 half-waves = 8 nodes per block
  const int lane = threadIdx.x & 31;
  const int ln = j * 8 + half;
  if (ln >= BLK) return;
  const int node = xg * BLK + ln;
  const int deg = count[node];
  const int* sl = csr + rowptr[node];
  int idx0 = (lane < deg) ? sl[lane] : 0;
  int idx1 = (32 + lane < deg) ? sl[32 + lane] : 0;
  float a0 = 0.f, a1 = 0.f, a2 = 0.f, a3 = 0.f;
  for (int e = 0; e < deg; ++e) {
    int srcn = (e < 32) ? __shfl(idx0, e, 32)
                        : ((e < 64) ? __shfl(idx1, e - 32, 32) : sl[e]);
    ushort4 v = *(const ushort4*)(xb + (size_t)srcn * HID + lane * 4);
    a0 += bf2f(v.x); a1 += bf2f(v.y); a2 += bf2f(v.z); a3 += bf2f(v.w);
  }
  ushort4 r;
  r.x = f2bf(a0); r.y = f2bf(a1); r.z = f2bf(a2); r.w = f2bf(a3);
  *(ushort4*)(aggb + (size_t)node * HID + lane * 4) = r;
}

// ---------------------------------------------------------------- K3: MFMA GEMM + softmax + pooled reductions
// R7 restructure: B fragments live in REGISTERS (Wt is 64 KB, L2-resident;
// each wave loads its 32-col x 256-K slice once = 16 bf16x8). A tile is
// double-buffered in LDS with a 3-deep register pipeline (ld(kt+3) issued
// ~2 iterations before its ds_write). One barrier per kt instead of two,
// and no B re-staging -> latency hidden instead of exposed on barriers.
__global__ __launch_bounds__(256) void k_fused(
    const ushort* __restrict__ aggb, const ushort* __restrict__ xb,
    const ushort* __restrict__ Wt, const float* __restrict__ brel1,
    const float* __restrict__ Wpool, const float* __restrict__ bpool,
    const int* __restrict__ count, float* __restrict__ s_out,
    float* __restrict__ out_pool, float* __restrict__ ss_g,
    float* __restrict__ den_g) {
  __shared__ ushort As[2][64][40];  // double-buffered A tile (pad 40)
  __shared__ float hL[64][132];     // h tile (pad 128->132)
  __shared__ float outL[KC][HID];
  __shared__ float ssL[16];
  __shared__ float denL;

  const int t = threadIdx.x;
  const int bG = blockIdx.x / CHUNKS;
  const int chunk = blockIdx.x % CHUNKS;
  const int node0 = bG * BLK + chunk * 64;
  int nrows = BLK - chunk * 64;
  if (nrows > 64) nrows = 64;

  for (int i = t; i < KC * HID; i += 256) ((float*)outL)[i] = 0.f;
  if (t < 16) ssL[t] = 0.f;
  if (t == 0) denL = 0.f;

  const int w = t >> 6;     // wave: cols 32w..32w+31
  const int l = t & 63;
  const int m16 = l & 15;
  const int gq = l >> 4;

  // ---- B fragments: registers, loaded once (L2-hot) ----
  bf16x8 Breg[8][2];
#pragma unroll
  for (int kt = 0; kt < 8; ++kt)
#pragma unroll
    for (int fc = 0; fc < 2; ++fc)
      Breg[kt][fc] =
          *(const bf16x8*)(Wt + (size_t)(32 * w + 16 * fc + m16) * 256 + kt * 32 + 8 * gq);

  // ---- A staging pipeline ----
  const int arow = t >> 2;
  const int acol = (t & 3) * 8;
  const int arr = (arow < nrows) ? arow : (nrows - 1);
  const ushort* Aag = aggb + (size_t)(node0 + arr) * HID + acol;
  const ushort* Axx = xb + (size_t)(node0 + arr) * HID + acol;
#define LDA(kt) (*(const uint4*)(((kt) < 4 ? Aag : Axx) + ((kt) & 3) * 32))

  uint4 r0 = LDA(0);
  *(uint4*)&As[0][arow][acol] = r0;
  uint4 rsA = LDA(1);
  uint4 rsB = LDA(2);

  f32x4 acc[4][2];
#pragma unroll
  for (int fr = 0; fr < 4; ++fr)
#pragma unroll
    for (int fc = 0; fc < 2; ++fc) acc[fr][fc] = (f32x4){0.f, 0.f, 0.f, 0.f};

  __syncthreads();

#pragma unroll
  for (int kt = 0; kt < 8; ++kt) {
    // write next tile into the other buffer (readers of it finished at kt-1's barrier)
    if (kt < 7) *(uint4*)&As[(kt + 1) & 1][arow][acol] = rsA;
    if (kt < 6) rsA = rsB;
    if (kt < 5) rsB = LDA(kt + 3);  // ~2 iterations of latency slack
    bf16x8 af[4];
#pragma unroll
    for (int fr = 0; fr < 4; ++fr)
      af[fr] = *(const bf16x8*)&As[kt & 1][16 * fr + m16][8 * gq];
#pragma unroll
    for (int fr = 0; fr < 4; ++fr)
#pragma unroll
      for (int fc = 0; fc < 2; ++fc)
        acc[fr][fc] = __builtin_amdgcn_mfma_f32_16x16x32_bf16(af[fr], Breg[kt][fc],
                                                              acc[fr][fc], 0, 0, 0);
    __syncthreads();
  }
#undef LDA

  // bias + relu -> hL  (D layout: row = 4*(l>>4)+reg, col = l&15  [m89])
  const float bc0 = brel1[32 * w + m16];
  const float bc1 = brel1[32 * w + 16 + m16];
#pragma unroll
  for (int fr = 0; fr < 4; ++fr)
#pragma unroll
    for (int fc = 0; fc < 2; ++fc)
#pragma unroll
      for (int r = 0; r < 4; ++r)
        hL[16 * fr + 4 * gq + r][32 * w + 16 * fc + m16] =
            fmaxf(acc[fr][fc][r] + (fc ? bc1 : bc0), 0.f);
  __syncthreads();

  // ---- epilogue (16-lane groups own 4 rows each) ----
  const int g4 = t >> 4;
  const int c0 = (t & 15) << 2;
  const int li = t & 15;

  float h[4][8];
#pragma unroll
  for (int r = 0; r < 4; ++r) {
    float4 v0 = *(const float4*)&hL[g4 * 4 + r][c0];
    float4 v1 = *(const float4*)&hL[g4 * 4 + r][c0 + 64];
    h[r][0] = v0.x; h[r][1] = v0.y; h[r][2] = v0.z; h[r][3] = v0.w;
    h[r][4] = v1.x; h[r][5] = v1.y; h[r][6] = v1.z; h[r][7] = v1.w;
  }

  // pooling head: p = h @ Wpool
  float wp[8][4];
#pragma unroll
  for (int j = 0; j < 8; ++j) {
    int col = c0 + (j & 3) + (j >> 2) * 64;
    float4 v = *(const float4*)(Wpool + col * 4);
    wp[j][0] = v.x; wp[j][1] = v.y; wp[j][2] = v.z; wp[j][3] = v.w;
  }
  float pp[4][4];
#pragma unroll
  for (int r = 0; r < 4; ++r)
#pragma unroll
    for (int k = 0; k < 4; ++k) pp[r][k] = 0.f;
#pragma unroll
  for (int r = 0; r < 4; ++r)
#pragma unroll
    for (int j = 0; j < 8; ++j)
#pragma unroll
      for (int k = 0; k < 4; ++k) pp[r][k] = fmaf(h[r][j], wp[j][k], pp[r][k]);
#pragma unroll
  for (int m = 1; m <= 8; m <<= 1)
#pragma unroll
    for (int r = 0; r < 4; ++r)
#pragma unroll
      for (int k = 0; k < 4; ++k) pp[r][k] += __shfl_xor(pp[r][k], m);

  float4 bp4 = *(const float4*)bpool;
  float bp[4] = {bp4.x, bp4.y, bp4.z, bp4.w};
  float sv[4][4];
#pragma unroll
  for (int r = 0; r < 4; ++r) {
    float p[4];
#pragma unroll
    for (int k = 0; k < 4; ++k) p[k] = pp[r][k] + bp[k];
    float mx = fmaxf(fmaxf(p[0], p[1]), fmaxf(p[2], p[3]));
    float e0 = expf(p[0] - mx), e1 = expf(p[1] - mx), e2 = expf(p[2] - mx), e3 = expf(p[3] - mx);
    float inv = 1.f / (e0 + e1 + e2 + e3);
    float valid = (g4 * 4 + r < nrows) ? 1.f : 0.f;
    sv[r][0] = e0 * inv * valid; sv[r][1] = e1 * inv * valid;
    sv[r][2] = e2 * inv * valid; sv[r][3] = e3 * inv * valid;
  }

  // write s
  {
    int rW = li >> 2, kW = li & 3;
    if (g4 * 4 + rW < nrows) {
      int node = node0 + g4 * 4 + rW;
      float val = 0.f;
#pragma unroll
      for (int rr = 0; rr < 4; ++rr)
#pragma unroll
        for (int kk = 0; kk < 4; ++kk)
          if (li == rr * 4 + kk) val = sv[rr][kk];
      s_out[node * 4 + kW] = val;
    }
  }

  // ss[b][k1][k2]
  {
    int k1 = li >> 2, k2 = li & 3;
    float a1[4], a2[4];
#pragma unroll
    for (int rr = 0; rr < 4; ++rr) {
      float v1 = 0.f, v2 = 0.f;
#pragma unroll
      for (int kk = 0; kk < 4; ++kk) {
        if (k1 == kk) v1 = sv[rr][kk];
        if (k2 == kk) v2 = sv[rr][kk];
      }
      a1[rr] = v1; a2[rr] = v2;
    }
    float ssv = a1[0] * a2[0] + a1[1] * a2[1] + a1[2] * a2[2] + a1[3] * a2[3];
    atomicAdd(&ssL[li], ssv);
  }

  // den[b] += deg * ||s||^2
  if (li == 0) {
    float dent = 0.f;
#pragma unroll
    for (int rr = 0; rr < 4; ++rr) {
      int rowg = g4 * 4 + rr;
      if (rowg < nrows) {
        float dg = (float)count[node0 + rowg];
        dent += dg * (sv[rr][0] * sv[rr][0] + sv[rr][1] * sv[rr][1] +
                      sv[rr][2] * sv[rr][2] + sv[rr][3] * sv[rr][3]);
      }
    }
    atomicAdd(&denL, dent);
  }

  // out[b][k][c] += s[r][k]*h[r][c]
  float po[4][8];
#pragma unroll
  for (int k = 0; k < 4; ++k)
#pragma unroll
    for (int c = 0; c < 8; ++c) po[k][c] = 0.f;
#pragma unroll
  for (int k = 0; k < 4; ++k)
#pragma unroll
    for (int rr = 0; rr < 4; ++rr)
#pragma unroll
      for (int c = 0; c < 8; ++c) po[k][c] = fmaf(sv[rr][k], h[rr][c], po[k][c]);
#pragma unroll
  for (int k = 0; k < 4; ++k)
#pragma unroll
    for (int c = 0; c < 8; ++c) {
      po[k][c] += __shfl_xor(po[k][c], 16);
      po[k][c] += __shfl_xor(po[k][c], 32);
    }
  if ((t & 63) < 16) {
#pragma unroll
    for (int k = 0; k < 4; ++k)
#pragma unroll
      for (int c = 0; c < 8; ++c)
        atomicAdd(&outL[k][c0 + (c & 3) + (c >> 2) * 64], po[k][c]);
  }

  __syncthreads();
  for (int i = t; i < KC * HID; i += 256)
    atomicAdd(&out_pool[bG * KC * HID + i], ((const float*)outL)[i]);
  if (t < 16) atomicAdd(&ss_g[bG * 16 + t], ssL[t]);
  if (t == 0) atomicAdd(&den_g[bG], denL);
}

// ---------------------------------------------------------------- K4: out_adj[b] = sum_n s[n] (x) t[n],  t[n] = sum_{e: dst=n} s[src]
__global__ __launch_bounds__(256) void k_adj2(const int* __restrict__ count,
                                              const int* __restrict__ rowptr,
                                              const int* __restrict__ csr,
                                              const float* __restrict__ s,
                                              float* __restrict__ adjraw) {
  __shared__ float accL[4][2][16];  // [wave][graph-within-block][k1*4+k2]
  const int t = threadIdx.x;
  if (t < 128) ((float*)accL)[t] = 0.f;
  __syncthreads();
  const int node = blockIdx.x * 256 + t;
  const int g0 = (blockIdx.x * 256) / BLK;
  if (node < NN) {
    const int gi = node / BLK - g0;  // 0 or 1
    const int deg = count[node];
    const int* sl = csr + rowptr[node];
    float t0 = 0.f, t1 = 0.f, t2 = 0.f, t3 = 0.f;
    for (int e = 0; e < deg; ++e) {
      float4 svv = *(const float4*)(s + (size_t)sl[e] * 4);
      t0 += svv.x; t1 += svv.y; t2 += svv.z; t3 += svv.w;
    }
    float4 sn = *(const float4*)(s + (size_t)node * 4);
    float* base = accL[t >> 6][gi];
#pragma unroll
    for (int i = 0; i < 16; ++i) {
      int idx = (i + t) & 15;  // stagger: 4-way instead of 64-way contention
      int hi = idx >> 2, lo = idx & 3;
      float a = (hi == 0) ? sn.x : (hi == 1) ? sn.y : (hi == 2) ? sn.z : sn.w;
      float b = (lo == 0) ? t0 : (lo == 1) ? t1 : (lo == 2) ? t2 : t3;
      atomicAdd(base + idx, a * b);
    }
  }
  __syncthreads();
  if (t < 32) {
    int gi = t >> 4, i = t & 15, gg = g0 + gi;
    if (gg < NB) {
      float v = accL[0][gi][i] + accL[1][gi][i] + accL[2][gi][i] + accL[3][gi][i];
      atomicAdd(&adjraw[gg * 16 + i], v);
    }
  }
}

// ---------------------------------------------------------------- K5a: per-graph tail
__global__ __launch_bounds__(128) void k_graph(
    const float* __restrict__ out_pool, const float* __restrict__ adjraw,
    const float* __restrict__ den_g, const float* __restrict__ ss_g,
    const float* __restrict__ Wrel3, const float* __restrict__ brel3,
    const float* __restrict__ Wroot3, const float* __restrict__ Wlin1,
    const float* __restrict__ blin1, const float* __restrict__ Wlin2,
    const float* __restrict__ blin2, float* __restrict__ d_out,
    float* __restrict__ scratch) {
  const int b = blockIdx.x, t = threadIdx.x;
  __shared__ float adjL[16], adjnL[16], dL[4];
  __shared__ float osL[128], msL[128], x2mL[128], x3L[128];
  if (t < 16) adjL[t] = adjraw[b * 16 + t];
  __syncthreads();
  if (t < 4) {
    float srow = 0.f;
#pragma unroll
    for (int l = 0; l < 4; ++l)
      if (l != t) srow += adjL[t * 4 + l];
    dL[t] = sqrtf(srow) + 1e-15f;
  }
  __syncthreads();
  if (t < 16) {
    int k1 = t >> 2, k2 = t & 3;
    float az = (k1 == k2) ? 0.f : adjL[t];
    float an = az / (dL[k2] * dL[k1]);
    adjnL[t] = an;
    d_out[400018 + b * 16 + t] = an;
  }
  __syncthreads();
  float o0 = out_pool[b * 512 + 0 * 128 + t];
  float o1 = out_pool[b * 512 + 1 * 128 + t];
  float o2 = out_pool[b * 512 + 2 * 128 + t];
  float o3 = out_pool[b * 512 + 3 * 128 + t];
  float m0 = adjnL[0] * o0 + adjnL[1] * o1 + adjnL[2] * o2 + adjnL[3] * o3;
  float m1 = adjnL[4] * o0 + adjnL[5] * o1 + adjnL[6] * o2 + adjnL[7] * o3;
  float m2 = adjnL[8] * o0 + adjnL[9] * o1 + adjnL[10] * o2 + adjnL[11] * o3;
  float m3 = adjnL[12] * o0 + adjnL[13] * o1 + adjnL[14] * o2 + adjnL[15] * o3;
  osL[t] = o0 + o1 + o2 + o3;
  msL[t] = m0 + m1 + m2 + m3;
  __syncthreads();
  float accc = brel3[t];
  for (int j = 0; j < 128; ++j)
    accc += 0.25f * (msL[j] * Wrel3[j * 128 + t] + osL[j] * Wroot3[j * 128 + t]);
  x2mL[t] = accc;
  __syncthreads();
  float a2 = blin1[t];
  for (int j = 0; j < 128; ++j) a2 += x2mL[j] * Wlin1[j * 128 + t];
  x3L[t] = fmaxf(a2, 0.f);
  __syncthreads();
  if (t < 2) {
    float lg = blin2[t];
    for (int j = 0; j < 128; ++j) lg += x3L[j] * Wlin2[j * 2 + t];
    scratch[b * 2 + t] = lg;
  }
  if (t == 0) {
    float tr = adjL[0] + adjL[5] + adjL[10] + adjL[15];
    scratch[16 + b] = tr / den_g[b];
    float n2 = 0.f;
    for (int i = 0; i < 16; ++i) { float v = ss_g[b * 16 + i]; n2 += v * v; }
    float nn = sqrtf(n2);
    float od = 0.f;
    for (int i = 0; i < 16; ++i) {
      float v = ss_g[b * 16 + i] / nn - (((i >> 2) == (i & 3)) ? 0.5f : 0.f);
      od += v * v;
    }
    scratch[24 + b] = sqrtf(od);
  }
}

// ---------------------------------------------------------------- K5b: losses + log_softmax
__global__ void k_final(const float* __restrict__ scratch, float* __restrict__ d_out) {
  if (threadIdx.x == 0 && blockIdx.x == 0) {
    float mc = 0.f, oo = 0.f;
    for (int b = 0; b < NB; ++b) { mc += scratch[16 + b]; oo += scratch[24 + b]; }
    d_out[16] = -(mc / (float)NB);
    d_out[17] = oo / (float)NB;
    for (int b = 0; b < NB; ++b) {
      float l0 = scratch[2 * b], l1 = scratch[2 * b + 1];
      float m = fmaxf(l0, l1);
      float lse = m + logf(expf(l0 - m) + expf(l1 - m));
      d_out[2 * b] = l0 - lse;
      d_out[2 * b + 1] = l1 - lse;
    }
  }
}

// ---------------------------------------------------------------- launch
extern "C" void kernel_launch(void* const* d_in, const int* in_sizes, int n_in,
                              void* d_out, int out_size, void* d_ws, size_t ws_size,
                              hipStream_t stream) {
  (void)in_sizes; (void)n_in; (void)out_size; (void)ws_size;
  const float* x      = (const float*)d_in[0];
  const int*   ei     = (const int*)d_in[1];
  const float* Wroot1 = (const float*)d_in[3];
  const float* Wrel1  = (const float*)d_in[4];
  const float* brel1  = (const float*)d_in[5];
  const float* Wpool  = (const float*)d_in[6];
  const float* bpool  = (const float*)d_in[7];
  const float* Wrel3  = (const float*)d_in[8];
  const float* brel3  = (const float*)d_in[9];
  const float* Wroot3 = (const float*)d_in[10];
  const float* Wlin1  = (const float*)d_in[11];
  const float* blin1  = (const float*)d_in[12];
  const float* Wlin2  = (const float*)d_in[13];
  const float* blin2  = (const float*)d_in[14];
  float* out = (float*)d_out;

  char* ws = (char*)d_ws;
  float*  out_pool = (float*)(ws + 0);          //  16384 B (memset)
  float*  ss_g     = (float*)(ws + 16384);      //    512 B (memset)
  float*  adjraw   = (float*)(ws + 16896);      //    512 B (memset)
  float*  den_g    = (float*)(ws + 17408);      //     32 B (memset)
  float*  scratch  = (float*)(ws + 17440);      //    128 B (memset)
  int*    sbcnt    = (int*)(ws + 17568);        //   1568 B (memset)
  int*    sbbase   = (int*)(ws + 19136);        //   1600 B
  int*    count    = (int*)(ws + 20736);        // 400000 B
  int*    rowptr   = (int*)(ws + 420736);       // 400016 B
  ushort* Wt       = (ushort*)(ws + 820752);    //  65536 B [128][256]
  int*    csr      = (int*)(ws + 886288);       // 6400000 B [E]
  ushort* xb       = (ushort*)(ws + 7286288);   // 25600000 B [N][128] bf16
  ushort* aggb     = (ushort*)(ws + 32886288);  // 25600000 B [N][128] bf16
  // gbuf (392 x 5120 x 4 B = 8.03 MB) aliases aggb: consumed by k_csr_tile
  // strictly before k_agg2 writes aggb (same stream, serialized).
  uint*   gbuf     = (uint*)(ws + 32886288);

  hipMemsetAsync(ws, 0, 19136, stream);
  k_prep_x<<<12500, 256, 0, stream>>>((const float4*)x, xb);
  k_prep_w<<<128, 256, 0, stream>>>(Wrel1, Wroot1, Wt);
  k_bucket2<<<196, 256, 0, stream>>>(ei, sbcnt, gbuf);
  k_scan392<<<1, 512, 0, stream>>>(sbcnt, sbbase);
  k_csr_tile<<<NBIN, 256, 0, stream>>>(gbuf, sbcnt, sbbase, rowptr, count, csr);
  k_agg2<<<8 * ((BLK + 7) / 8), 256, 0, stream>>>(xb, count, rowptr, csr, aggb);
  k_fused<<<NB * CHUNKS, 256, 0, stream>>>(aggb, xb, Wt, brel1, Wpool, bpool, count,
                                           out + 18, out_pool, ss_g, den_g);
  k_adj2<<<(NN + 255) / 256, 256, 0, stream>>>(count, rowptr, csr, out + 18, adjraw);
  k_graph<<<NB, 128, 0, stream>>>(out_pool, adjraw, den_g, ss_g, Wrel3, brel3, Wroot3,
                                  Wlin1, blin1, Wlin2, blin2, out, scratch);
  k_final<<<1, 64, 0, stream>>>(scratch, out);
}